// Round 16
// baseline (630.968 us; speedup 1.0000x reference)
//
#include <hip/hip_runtime.h>
#include <hip/hip_bf16.h>
#include <hip/hip_fp16.h>
#include <math.h>

#define NB 32
#define NL 1024
#define NG 3
#define ND 384
#define NH 96
#define NDG 192
#define SEQR 3073   // 1 + G*L

typedef __attribute__((ext_vector_type(8))) short short8n;
typedef __attribute__((ext_vector_type(4))) short short4n;
typedef __attribute__((ext_vector_type(8))) _Float16 half8n;
typedef __attribute__((ext_vector_type(4))) float f32x4;
typedef __attribute__((ext_vector_type(4))) unsigned int uint4n;

__device__ __forceinline__ short bfx(float f) {
  __hip_bfloat16 h = __float2bfloat16(f);
  return *reinterpret_cast<short*>(&h);
}
__device__ __forceinline__ float xbf(short s) {
  __hip_bfloat16 h = *reinterpret_cast<__hip_bfloat16*>(&s);
  return __bfloat162float(h);
}
__device__ __forceinline__ short hfx(float f) {
  __half h = __float2half(f);
  return *reinterpret_cast<short*>(&h);
}
__device__ __forceinline__ float xhf(short s) {
  __half h = *reinterpret_cast<__half*>(&s);
  return __half2float(h);
}

// fast atan2, abs err <= ~1e-5 rad
__device__ __forceinline__ float fast_atan2f(float y, float x) {
  float ax = fabsf(x), ay = fabsf(y);
  float mx = fmaxf(ax, ay), mn = fminf(ax, ay);
  float r = (mx == 0.0f) ? 0.0f : __fdividef(mn, mx);
  float s = r * r;
  float p = fmaf(s, 0.0208351f, -0.0851330f);
  p = fmaf(s, p, 0.1801410f);
  p = fmaf(s, p, -0.3302995f);
  p = fmaf(s, p, 0.9998660f);
  p = r * p;
  float a = (ay > ax) ? (1.5707963267948966f - p) : p;
  a = (x < 0.0f) ? (3.14159265358979323846f - a) : a;
  return (y < 0.0f) ? -a : a;
}

__device__ __forceinline__ float fast_sigmoid(float x) {
  return __fdividef(1.0f, 1.0f + __expf(-x));
}
__device__ __forceinline__ float fast_tanh(float x) {
  return 1.0f - __fdividef(2.0f, 1.0f + __expf(2.0f * x));
}

// FFT LDS swizzles: break power-of-2 stride bank patterns
__device__ __forceinline__ int swzd(int p) { return p + (p >> 5); }  // data (max 1054)
__device__ __forceinline__ int swzt(int t) { return t + (t >> 4); }  // twiddle (max 814)

// base-4 digit reversal of a 10-bit index (5 digits)
__device__ __forceinline__ int rev4_10(int p) {
  unsigned q = (unsigned)p, r = 0;
#pragma unroll
  for (int i = 0; i < 5; i++) { r = (r << 2) | (q & 3); q >>= 2; }
  return (int)r;
}

// DIF radix-4 butterfly (fwd): in-place on A,B,C,D with twiddles w1,w2,w3
__device__ __forceinline__ void bfly_dif(float2& A, float2& B, float2& C, float2& D,
                                         float2 w1, float2 w2, float2 w3) {
  float t0r = A.x + C.x, t0i = A.y + C.y;
  float t1r = A.x - C.x, t1i = A.y - C.y;
  float t2r = B.x + D.x, t2i = B.y + D.y;
  float t3r = B.x - D.x, t3i = B.y - D.y;
  A = make_float2(t0r + t2r, t0i + t2i);
  float y1r = t1r + t3i, y1i = t1i - t3r;
  float y2r = t0r - t2r, y2i = t0i - t2i;
  float y3r = t1r - t3i, y3i = t1i + t3r;
  B = make_float2(y1r * w1.x - y1i * w1.y, y1r * w1.y + y1i * w1.x);
  C = make_float2(y2r * w2.x - y2i * w2.y, y2r * w2.y + y2i * w2.x);
  D = make_float2(y3r * w3.x - y3i * w3.y, y3r * w3.y + y3i * w3.x);
}

// DIT radix-4 butterfly (inv): conj-twiddle inputs B,C,D then combine
__device__ __forceinline__ void bfly_dit(float2& A, float2& B, float2& C, float2& D,
                                         float2 w1, float2 w2, float2 w3) {
  float bpr = B.x * w1.x + B.y * w1.y, bpi = B.y * w1.x - B.x * w1.y;
  float cpr = C.x * w2.x + C.y * w2.y, cpi = C.y * w2.x - C.x * w2.y;
  float dpr = D.x * w3.x + D.y * w3.y, dpi = D.y * w3.x - D.x * w3.y;
  float t0r = A.x + cpr, t0i = A.y + cpi;
  float t1r = A.x - cpr, t1i = A.y - cpi;
  float t2r = bpr + dpr, t2i = bpi + dpi;
  float er = bpr - dpr, ei = bpi - dpi;
  float t3r = -ei, t3i = er;
  A = make_float2(t0r + t2r, t0i + t2i);
  B = make_float2(t1r + t3r, t1i + t3i);
  C = make_float2(t0r - t2r, t0i - t2i);
  D = make_float2(t1r - t3r, t1i - t3i);
}

// DIT radix-4 butterfly, twiddle-free (e=0)
__device__ __forceinline__ void bfly_dit0(float2& A, float2& B, float2& C, float2& D) {
  float t0r = A.x + C.x, t0i = A.y + C.y;
  float t1r = A.x - C.x, t1i = A.y - C.y;
  float t2r = B.x + D.x, t2i = B.y + D.y;
  float er = B.x - D.x, ei = B.y - D.y;
  float t3r = -ei, t3i = er;
  A = make_float2(t0r + t2r, t0i + t2i);
  B = make_float2(t1r + t3r, t1i + t3i);
  C = make_float2(t0r - t2r, t0i - t2i);
  D = make_float2(t1r - t3r, t1i - t3i);
}

// ---------------------------------------------------------------- prep
__global__ __launch_bounds__(256) void k_prep(const float* __restrict__ convW,
                                              const float* __restrict__ x,
                                              const float* __restrict__ mgW1s,
                                              const float* __restrict__ phW1s,
                                              const float* __restrict__ mgW2s,
                                              const float* __restrict__ phW2s,
                                              const float* __restrict__ cgW1s,
                                              __hip_bfloat16* __restrict__ Wt2,
                                              float* __restrict__ twid,
                                              __half* __restrict__ W1Ao,
                                              __half* __restrict__ W2Ao,
                                              __hip_bfloat16* __restrict__ W1Go,
                                              float* __restrict__ outp) {
  int id = blockIdx.x * 256 + threadIdx.x;
  if (id < 384 * 384 * 3) {
    int i = id % 384; int rest = id / 384; int o = rest % 384; int kh = rest / 384;
    Wt2[id] = __float2bfloat16(convW[(o * 384 + i) * 3 + kh]);
    return;
  }
  int id2 = id - 384 * 384 * 3;
  if (id2 < 1024) {    // full-circle twiddle table (radix-4 needs up to W^765)
    float ang = -6.283185307179586f * (float)id2 / 1024.0f;
    float s, c; sincosf(ang, &s, &c);
    twid[2 * id2] = c; twid[2 * id2 + 1] = s;
    return;
  }
  int id3 = id2 - 1024;
  if (id3 < NB * ND) {
    int b = id3 / ND, d = id3 % ND;
    outp[(size_t)b * SEQR * ND + d] = x[(size_t)b * SEQR * ND + d];
    return;
  }
  int id4 = id3 - NB * ND;
  if (id4 < 2 * 36864) {   // W1A (fp16): [br][kk(12)][f(6)][lane(64)][8]
    int br = id4 / 36864, idx = id4 % 36864;
    int j = idx & 7, ln = (idx >> 3) & 63, rest = idx >> 9;
    int f = rest % 6, kk = rest / 6;
    int m = f * 16 + (ln & 15), k = kk * 32 + (ln >> 4) * 8 + j;
    const float* W = br ? phW1s : mgW1s;
    W1Ao[id4] = __float2half(W[k * NH + m]);
    return;
  }
  int id5 = id4 - 2 * 36864;
  if (id5 < 2 * 36864) {   // W2A (fp16): [br][kk(3)][f(24)][lane(64)][8]
    int br = id5 / 36864, idx = id5 % 36864;
    int j = idx & 7, ln = (idx >> 3) & 63, rest = idx >> 9;
    int f = rest % 24, kk = rest / 24;
    int d = f * 16 + (ln & 15), k = kk * 32 + (ln >> 4) * 8 + j;
    const float* W = br ? phW2s : mgW2s;
    W2Ao[id5] = __float2half(W[k * ND + d]);
    return;
  }
  int id6 = id5 - 2 * 36864;
  if (id6 < 147456) {      // W1G: [part(2)][kk(12)][f(12)][lane(64)][8]
    int j = id6 & 7, ln = (id6 >> 3) & 63, rest = id6 >> 9;
    int f = rest % 12, rest2 = rest / 12;
    int kk = rest2 % 12, part = rest2 / 12;
    int m = f * 16 + (ln & 15), k = part * 384 + kk * 32 + (ln >> 4) * 8 + j;
    W1Go[id6] = __float2bfloat16(cgW1s[k * NDG + m]);
  }
}

// ---------------------------------------------------------------- gate MLP via MFMA
__global__ __launch_bounds__(256) void k_gate2(const float* __restrict__ x,
    const __hip_bfloat16* __restrict__ W1G,
    const float* __restrict__ b1, const float* __restrict__ gam,
    const float* __restrict__ bet, const float* __restrict__ W2,
    const float* __restrict__ b2p,
    __hip_bfloat16* __restrict__ gatedA) {
  int bid = blockIdx.x;
  int b = bid >> 6; int l0 = (bid & 63) * 16;
  int tid = threadIdx.x;
  int lane = tid & 63, wid = tid >> 6;
  int r15 = lane & 15, kc = lane >> 4;

  __shared__ short xs[3][16][392];
  __shared__ short gs[16][392];
  __shared__ float hG[16][196];
  __shared__ float s_b1[NDG], s_g[NDG], s_be[NDG], s_w2[NDG];
  __shared__ float sgate[3][16];

  if (tid < NDG) {
    s_b1[tid] = b1[tid]; s_g[tid] = gam[tid];
    s_be[tid] = bet[tid]; s_w2[tid] = W2[tid];
  }
  for (int c = tid; c < 16 * 96; c += 256) {
    int l = c / 96, d4 = (c % 96) * 4;
    size_t base = ((size_t)b * SEQR + 1 + l0 + l) * ND + d4;
    float4 v0 = *reinterpret_cast<const float4*>(&x[base]);
    float4 v1 = *reinterpret_cast<const float4*>(&x[base + (size_t)NL * ND]);
    float4 v2 = *reinterpret_cast<const float4*>(&x[base + (size_t)2 * NL * ND]);
    short4n q0, q1, q2, qg;
    q0.x = bfx(v0.x); q0.y = bfx(v0.y); q0.z = bfx(v0.z); q0.w = bfx(v0.w);
    q1.x = bfx(v1.x); q1.y = bfx(v1.y); q1.z = bfx(v1.z); q1.w = bfx(v1.w);
    q2.x = bfx(v2.x); q2.y = bfx(v2.y); q2.z = bfx(v2.z); q2.w = bfx(v2.w);
    qg.x = bfx((v0.x + v1.x + v2.x) * (1.0f / 3.0f));
    qg.y = bfx((v0.y + v1.y + v2.y) * (1.0f / 3.0f));
    qg.z = bfx((v0.z + v1.z + v2.z) * (1.0f / 3.0f));
    qg.w = bfx((v0.w + v1.w + v2.w) * (1.0f / 3.0f));
    *reinterpret_cast<short4n*>(&xs[0][l][d4]) = q0;
    *reinterpret_cast<short4n*>(&xs[1][l][d4]) = q1;
    *reinterpret_cast<short4n*>(&xs[2][l][d4]) = q2;
    *reinterpret_cast<short4n*>(&gs[l][d4]) = qg;
  }
  __syncthreads();

  const short* bsrc = (wid == 3) ? &gs[0][0] : &xs[wid][0][0];
  const __hip_bfloat16* W1b = W1G + (size_t)(wid == 3 ? 1 : 0) * 73728;
  f32x4 hacc[12];
#pragma unroll
  for (int f = 0; f < 12; f++)
#pragma unroll
    for (int j = 0; j < 4; j++)
      hacc[f][j] = (wid == 3) ? 0.0f : s_b1[f * 16 + kc * 4 + j];
  for (int kk = 0; kk < 12; kk++) {
    short8n bx = *reinterpret_cast<const short8n*>(&bsrc[r15 * 392 + kk * 32 + kc * 8]);
#pragma unroll
    for (int f = 0; f < 12; f++) {
      short8n aw = *reinterpret_cast<const short8n*>(
          (const void*)(W1b + (((size_t)kk * 12 + f) * 64 + lane) * 8));
      hacc[f] = __builtin_amdgcn_mfma_f32_16x16x32_bf16(aw, bx, hacc[f], 0, 0, 0);
    }
  }
  if (wid == 3) {
#pragma unroll
    for (int f = 0; f < 12; f++)
#pragma unroll
      for (int j = 0; j < 4; j++)
        hG[r15][f * 16 + kc * 4 + j] = hacc[f][j];
  }
  __syncthreads();
  if (wid < 3) {
    float s = 0.f, sq = 0.f;
#pragma unroll
    for (int f = 0; f < 12; f++)
#pragma unroll
      for (int j = 0; j < 4; j++) {
        float v = hacc[f][j] + hG[r15][f * 16 + kc * 4 + j];
        hacc[f][j] = v; s += v; sq += v * v;
      }
    s += __shfl_xor(s, 16, 64); s += __shfl_xor(s, 32, 64);
    sq += __shfl_xor(sq, 16, 64); sq += __shfl_xor(sq, 32, 64);
    float mean = s * (1.0f / NDG);
    float var = sq * (1.0f / NDG) - mean * mean;
    float rstd = rsqrtf(var + 1e-5f);
    float dot = 0.f;
#pragma unroll
    for (int f = 0; f < 12; f++)
#pragma unroll
      for (int j = 0; j < 4; j++) {
        int m = f * 16 + kc * 4 + j;
        float hn = fmaxf((hacc[f][j] - mean) * rstd * s_g[m] + s_be[m], 0.0f);
        dot += hn * s_w2[m];
      }
    dot += __shfl_xor(dot, 16, 64); dot += __shfl_xor(dot, 32, 64);
    float gate = fast_sigmoid(dot + b2p[0]);
    if (lane < 16) sgate[wid][r15] = gate;
  }
  __syncthreads();
  if (wid < 3) {
    size_t obase = (((size_t)b * NG + wid) * NL + l0) * ND;
    for (int c = lane; c < 16 * 96; c += 64) {
      int l = c / 96, d4 = (c % 96) * 4;
      float gt = sgate[wid][l];
      short4n qx = *reinterpret_cast<const short4n*>(&xs[wid][l][d4]);
      short4n qg = *reinterpret_cast<const short4n*>(&gs[l][d4]);
      short4n qo;
#pragma unroll
      for (int j = 0; j < 4; j++) {
        float xv = xbf(((short*)&qx)[j]);
        float gv = xbf(((short*)&qg)[j]);
        ((short*)&qo)[j] = bfx(xv * gt + gv * (1.0f - gt));
      }
      *reinterpret_cast<short4n*>(&((short*)gatedA)[obase + (size_t)l * ND + d4]) = qo;
    }
  }
}

// ---------------------------------------------------------------- conv as bf16 MFMA GEMM
// output written TRANSPOSED as fp16: reh[(b*SEQR+1)*768 + (g*384+d)*NL + l]
#define BKC 64
__global__ __launch_bounds__(256) void k_conv_mfma(
    const __hip_bfloat16* __restrict__ Abuf,
    const __hip_bfloat16* __restrict__ Wt2,
    const float* __restrict__ cb,
    __half* __restrict__ reh) {
  int bid = blockIdx.x;
  int ct = bid % 3; int rest = bid / 3;
  int rt = rest % 8; int bg = rest / 8;
  int b = bg / NG, gg = bg % NG;
  int l0 = rt * 128;
  int n0 = ct * 128;
  int tid = threadIdx.x;
  int lane = tid & 63, wid = tid >> 6;
  int wr = wid >> 1, wc = wid & 1;
  int r15 = lane & 15, kc = lane >> 4;

  __shared__ short As[128 * BKC];
  __shared__ short Bs[128 * BKC];

  f32x4 acc[4][4];
#pragma unroll
  for (int m = 0; m < 4; m++)
#pragma unroll
    for (int n = 0; n < 4; n++) acc[m][n] = (f32x4){0.f, 0.f, 0.f, 0.f};

  for (int kh = 0; kh < 3; kh++) {
    int gs = gg + kh - 1;
    if (gs < 0 || gs >= NG) continue;
    const __hip_bfloat16* Ag = Abuf + (((size_t)b * NG + gs) * NL + l0) * ND;
    const __hip_bfloat16* Bg = Wt2 + ((size_t)kh * 384 + n0) * 384;
    for (int k0 = 0; k0 < 384; k0 += BKC) {
      __syncthreads();
#pragma unroll
      for (int p = 0; p < 4; p++) {
        int idx = p * 256 + tid;
        int row = idx >> 3, c = idx & 7;
        int csrc = c ^ (row & 7);
        __builtin_amdgcn_global_load_lds(
            (const __attribute__((address_space(1))) void*)(Ag + (size_t)row * ND + k0 + csrc * 8),
            (__attribute__((address_space(3))) void*)(&As[idx * 8]), 16, 0, 0);
      }
#pragma unroll
      for (int p = 0; p < 4; p++) {
        int idx = p * 256 + tid;
        int row = idx >> 3, c = idx & 7;
        int csrc = c ^ (row & 7);
        __builtin_amdgcn_global_load_lds(
            (const __attribute__((address_space(1))) void*)(Bg + (size_t)row * 384 + k0 + csrc * 8),
            (__attribute__((address_space(3))) void*)(&Bs[idx * 8]), 16, 0, 0);
      }
      __syncthreads();
#pragma unroll
      for (int ks = 0; ks < 2; ks++) {
        short8n af[4], bfr[4];
        int cdata = ks * 4 + kc;
#pragma unroll
        for (int m = 0; m < 4; m++) {
          int row = wr * 64 + m * 16 + r15;
          af[m] = *reinterpret_cast<const short8n*>(&As[row * 64 + (cdata ^ (row & 7)) * 8]);
          int col = wc * 64 + m * 16 + r15;
          bfr[m] = *reinterpret_cast<const short8n*>(&Bs[col * 64 + (cdata ^ (col & 7)) * 8]);
        }
#pragma unroll
        for (int m = 0; m < 4; m++)
#pragma unroll
          for (int n = 0; n < 4; n++)
            acc[m][n] = __builtin_amdgcn_mfma_f32_16x16x32_bf16(af[m], bfr[n], acc[m][n], 0, 0, 0);
      }
    }
  }
  // transposed fp16 epilogue: lane holds 4 consecutive l for fixed d -> ushort4 along l
  float cbv[4];
#pragma unroll
  for (int n = 0; n < 4; n++) cbv[n] = cb[n0 + wc * 64 + n * 16 + r15];
  size_t tbase = ((size_t)b * SEQR + 1) * (size_t)(ND * 2);   // half index of row 1
#pragma unroll
  for (int n = 0; n < 4; n++) {
    int drow = gg * ND + n0 + wc * 64 + n * 16 + r15;
#pragma unroll
    for (int m = 0; m < 4; m++) {
      int lcol = l0 + wr * 64 + m * 16 + kc * 4;
      short4n hv;
      hv.x = hfx(acc[m][n][0] + cbv[n]);
      hv.y = hfx(acc[m][n][1] + cbv[n]);
      hv.z = hfx(acc[m][n][2] + cbv[n]);
      hv.w = hfx(acc[m][n][3] + cbv[n]);
      *reinterpret_cast<short4n*>(&reh[tbase + (size_t)drow * NL + lcol]) = hv;
    }
  }
}

// ---------------------------------------------------------------- FFT fwd: radix-4 DIF fused 2-stage passes
// input fp16 re; output packed fp16 (mag,phase) into MG[d][l]; DC-bin re into dcre
__global__ __launch_bounds__(256) void k_fft_fwd(const float* __restrict__ twid,
                                                 const __half* __restrict__ reh,
                                                 unsigned int* __restrict__ MG,
                                                 float* __restrict__ dcre) {
  int bid = blockIdx.x;
  int b = bid / 288;
  int rloc = (bid % 288) * 4;
  size_t rbase = ((size_t)b * SEQR + 1) * (size_t)(ND * 2) + (size_t)rloc * NL;
  size_t ibase = ((size_t)b * NG * ND + rloc) * NL;
  int tid = threadIdx.x;
  __shared__ float2 sc[4][1056];
  __shared__ float2 stw[816];
  for (int t = tid; t < 768; t += 256)
    stw[swzt(t)] = make_float2(twid[2 * t], twid[2 * t + 1]);
  // batched load: all 8 loads in flight, then unpack
  {
    unsigned wv[8];
#pragma unroll
    for (int u = 0; u < 8; u++) {
      int idx = tid + u * 256;
      int line = idx >> 9, pp = idx & 511;
      wv[u] = *reinterpret_cast<const unsigned*>(&reh[rbase + (size_t)line * NL + pp * 2]);
    }
#pragma unroll
    for (int u = 0; u < 8; u++) {
      int idx = tid + u * 256;
      int line = idx >> 9, pp = idx & 511;
      sc[line][swzd(pp * 2)]     = make_float2(xhf((short)(wv[u] & 0xffffu)), 0.0f);
      sc[line][swzd(pp * 2 + 1)] = make_float2(xhf((short)(wv[u] >> 16)), 0.0f);
    }
  }
  __syncthreads();
  int line = tid >> 6;
  // ---- pass A: stages m=256 (s2=8), m=64 (s2=6)
  {
    int jjp = tid & 63;
    float2 X[4][4];
#pragma unroll
    for (int a = 0; a < 4; a++)
#pragma unroll
      for (int c = 0; c < 4; c++)
        X[a][c] = sc[line][swzd(a * 256 + c * 64 + jjp)];
#pragma unroll
    for (int c = 0; c < 4; c++) {       // stage m=256 over a; e = (c*64+jjp)
      int e = c * 64 + jjp;
      bfly_dif(X[0][c], X[1][c], X[2][c], X[3][c],
               stw[swzt(e)], stw[swzt(2 * e)], stw[swzt(3 * e)]);
    }
    {                                   // stage m=64 over c; e = jjp<<2
      int e = jjp << 2;
      float2 w1 = stw[swzt(e)], w2 = stw[swzt(2 * e)], w3 = stw[swzt(3 * e)];
#pragma unroll
      for (int a = 0; a < 4; a++)
        bfly_dif(X[a][0], X[a][1], X[a][2], X[a][3], w1, w2, w3);
    }
#pragma unroll
    for (int a = 0; a < 4; a++)
#pragma unroll
      for (int c = 0; c < 4; c++)
        sc[line][swzd(a * 256 + c * 64 + jjp)] = X[a][c];
  }
  __syncthreads();
  // ---- pass B: stages m=16 (s2=4), m=4 (s2=2)
  {
    int idx = tid & 63;
    int g = idx >> 2, jjp = idx & 3;
    int base = g * 64 + jjp;
    float2 X[4][4];
#pragma unroll
    for (int a = 0; a < 4; a++)
#pragma unroll
      for (int c = 0; c < 4; c++)
        X[a][c] = sc[line][swzd(base + a * 16 + c * 4)];
#pragma unroll
    for (int c = 0; c < 4; c++) {       // stage m=16 over a; e = (4c+jjp)<<4
      int e = (c * 4 + jjp) << 4;
      bfly_dif(X[0][c], X[1][c], X[2][c], X[3][c],
               stw[swzt(e)], stw[swzt(2 * e)], stw[swzt(3 * e)]);
    }
    {                                   // stage m=4 over c; e = jjp<<6
      int e = jjp << 6;
      float2 w1 = stw[swzt(e)], w2 = stw[swzt(2 * e)], w3 = stw[swzt(3 * e)];
#pragma unroll
      for (int a = 0; a < 4; a++)
        bfly_dif(X[a][0], X[a][1], X[a][2], X[a][3], w1, w2, w3);
    }
#pragma unroll
    for (int a = 0; a < 4; a++)
#pragma unroll
      for (int c = 0; c < 4; c++)
        sc[line][swzd(base + a * 16 + c * 4)] = X[a][c];
  }
  __syncthreads();
  // ---- pass C: stage m=1 (twiddle-free)
#pragma unroll
  for (int u = 0; u < 4; u++) {
    int p0 = tid * 4;
    float2 A = sc[u][swzd(p0)], B = sc[u][swzd(p0 + 1)];
    float2 C = sc[u][swzd(p0 + 2)], D = sc[u][swzd(p0 + 3)];
    float t0r = A.x + C.x, t0i = A.y + C.y;
    float t1r = A.x - C.x, t1i = A.y - C.y;
    float t2r = B.x + D.x, t2i = B.y + D.y;
    float t3r = B.x - D.x, t3i = B.y - D.y;
    sc[u][swzd(p0)]     = make_float2(t0r + t2r, t0i + t2i);
    sc[u][swzd(p0 + 1)] = make_float2(t1r + t3i, t1i - t3r);
    sc[u][swzd(p0 + 2)] = make_float2(t0r - t2r, t0i - t2i);
    sc[u][swzd(p0 + 3)] = make_float2(t1r - t3i, t1i + t3r);
  }
  __syncthreads();
  for (int idx = tid; idx < 4096; idx += 256) {
    int li = idx >> 10, pos = idx & 1023;
    float2 v = sc[li][swzd(pos)];
    unsigned mg = (unsigned)(unsigned short)hfx(sqrtf(v.x * v.x + v.y * v.y));
    unsigned ph = (unsigned)(unsigned short)hfx(fast_atan2f(v.y, v.x));
    MG[ibase + (size_t)li * NL + pos] = mg | (ph << 16);
    if (pos == 0) dcre[b * NG * ND + rloc + li] = v.x;   // DC bin (digit-rev(0)=0)
  }
}

// ---------------------------------------------------------------- FFT inv: radix-4 DIT fused 2-stage passes
// input: packed fp16 (P,Q) in MG; re=P*cos(Q), im=P*sin(Q); writes packed fp16 real in place
__global__ __launch_bounds__(256) void k_fft_inv(const float* __restrict__ twid,
                                                 unsigned int* __restrict__ MG) {
  int bid = blockIdx.x;
  int b = bid / 288;
  int rloc = (bid % 288) * 4;
  size_t ibase = ((size_t)b * NG * ND + rloc) * NL;
  int tid = threadIdx.x;
  __shared__ float2 sc[4][1056];
  __shared__ float2 stw[816];
  for (int t = tid; t < 768; t += 256)
    stw[swzt(t)] = make_float2(twid[2 * t], twid[2 * t + 1]);
  // batched load: two groups of 8 loads in flight
#pragma unroll
  for (int g = 0; g < 2; g++) {
    unsigned wv[8];
#pragma unroll
    for (int u = 0; u < 8; u++) {
      int idx = tid + (g * 8 + u) * 256;
      int lineu = idx >> 10, pos = idx & 1023;
      wv[u] = MG[ibase + (size_t)lineu * NL + pos];
    }
#pragma unroll
    for (int u = 0; u < 8; u++) {
      int idx = tid + (g * 8 + u) * 256;
      int lineu = idx >> 10, pos = idx & 1023;
      float P = xhf((short)(wv[u] & 0xffff));
      float Q = xhf((short)(wv[u] >> 16));
      sc[lineu][swzd(pos)] = make_float2(P * __cosf(Q), P * __sinf(Q));
    }
  }
  __syncthreads();
  int line = tid >> 6;
  // ---- pass A: stages m=1 (e=0), m=4
  {
    int G = tid & 63;
    int base = G * 16;
    float2 X[4][4];                      // X[q][r]
#pragma unroll
    for (int q = 0; q < 4; q++)
#pragma unroll
      for (int r = 0; r < 4; r++)
        X[q][r] = sc[line][swzd(base + q * 4 + r)];
#pragma unroll
    for (int q = 0; q < 4; q++)          // stage m=1 over r, twiddle-free
      bfly_dit0(X[q][0], X[q][1], X[q][2], X[q][3]);
#pragma unroll
    for (int r = 0; r < 4; r++) {        // stage m=4 over q; e = r<<6
      int e = r << 6;
      bfly_dit(X[0][r], X[1][r], X[2][r], X[3][r],
               stw[swzt(e)], stw[swzt(2 * e)], stw[swzt(3 * e)]);
    }
#pragma unroll
    for (int q = 0; q < 4; q++)
#pragma unroll
      for (int r = 0; r < 4; r++)
        sc[line][swzd(base + q * 4 + r)] = X[q][r];
  }
  __syncthreads();
  // ---- pass B: stages m=16, m=64
  {
    int idx = tid & 63;
    int G = idx >> 4, jj = idx & 15;
    int base = G * 256 + jj;
    float2 X[4][4];                      // X[k][u]
#pragma unroll
    for (int k = 0; k < 4; k++)
#pragma unroll
      for (int u = 0; u < 4; u++)
        X[k][u] = sc[line][swzd(base + u * 64 + k * 16)];
    {                                    // stage m=16 over k; e = jj<<4 (same all u)
      int e = jj << 4;
      float2 w1 = stw[swzt(e)], w2 = stw[swzt(2 * e)], w3 = stw[swzt(3 * e)];
#pragma unroll
      for (int u = 0; u < 4; u++)
        bfly_dit(X[0][u], X[1][u], X[2][u], X[3][u], w1, w2, w3);
    }
#pragma unroll
    for (int k = 0; k < 4; k++) {        // stage m=64 over u; e = (16k+jj)<<2
      int e = (k * 16 + jj) << 2;
      bfly_dit(X[k][0], X[k][1], X[k][2], X[k][3],
               stw[swzt(e)], stw[swzt(2 * e)], stw[swzt(3 * e)]);
    }
#pragma unroll
    for (int k = 0; k < 4; k++)
#pragma unroll
      for (int u = 0; u < 4; u++)
        sc[line][swzd(base + u * 64 + k * 16)] = X[k][u];
  }
  __syncthreads();
  // ---- pass C: stage m=256
#pragma unroll
  for (int u = 0; u < 4; u++) {
    int jj = tid;                        // 0..255
    int e = jj;
    float2 A = sc[u][swzd(jj)],       B = sc[u][swzd(jj + 256)];
    float2 C = sc[u][swzd(jj + 512)], D = sc[u][swzd(jj + 768)];
    bfly_dit(A, B, C, D, stw[swzt(e)], stw[swzt(2 * e)], stw[swzt(3 * e)]);
    sc[u][swzd(jj)] = A; sc[u][swzd(jj + 256)] = B;
    sc[u][swzd(jj + 512)] = C; sc[u][swzd(jj + 768)] = D;
  }
  __syncthreads();
  const float scf = 1.0f / 1024.0f;
  for (int idx = tid; idx < 2048; idx += 256) {
    int li = idx >> 9, pp = idx & 511;
    unsigned lo = (unsigned)(unsigned short)hfx(sc[li][swzd(2 * pp)].x * scf);
    unsigned hi = (unsigned)(unsigned short)hfx(sc[li][swzd(2 * pp + 1)].x * scf);
    MG[(ibase + (size_t)li * NL) / 2 + pp] = lo | (hi << 16);
  }
}

// ---------------------------------------------------------------- final transpose fp16 [d][l] -> fp32 [l][d]
__global__ __launch_bounds__(256) void k_tr(const __half* __restrict__ src,
                                            float* __restrict__ dst) {
  int bid = blockIdx.x;
  int dt = bid % 6; int r1 = bid / 6;
  int lt = r1 % 16; int r2 = r1 / 16;
  int gg = r2 % NG; int b = r2 / NG;
  int tid = threadIdx.x;
  __shared__ float T[64][67];
  size_t sbase = ((size_t)b * NG * ND + gg * ND + dt * 64) * NL + lt * 64;
  // batched loads
  {
    uint2 wv[4];
#pragma unroll
    for (int u = 0; u < 4; u++) {
      int c = tid + u * 256;
      int r = c >> 4, cc = c & 15;
      wv[u] = *reinterpret_cast<const uint2*>(&src[sbase + (size_t)r * NL + cc * 4]);
    }
#pragma unroll
    for (int u = 0; u < 4; u++) {
      int c = tid + u * 256;
      int r = c >> 4, cc = c & 15;
      T[r][cc * 4 + 0] = xhf((short)(wv[u].x & 0xffffu));
      T[r][cc * 4 + 1] = xhf((short)(wv[u].x >> 16));
      T[r][cc * 4 + 2] = xhf((short)(wv[u].y & 0xffffu));
      T[r][cc * 4 + 3] = xhf((short)(wv[u].y >> 16));
    }
  }
  __syncthreads();
  size_t dbase = ((size_t)b * SEQR + 1 + (size_t)gg * NL + lt * 64) * ND + dt * 64;
  for (int c = tid; c < 64 * 16; c += 256) {
    int r = c >> 4, cc = c & 15;
    float4 v = {T[cc * 4 + 0][r], T[cc * 4 + 1][r], T[cc * 4 + 2][r], T[cc * 4 + 3][r]};
    *reinterpret_cast<float4*>(&dst[dbase + (size_t)r * ND + cc * 4]) = v;
  }
}

// ---------------------------------------------------------------- band MLP (reads dcre side buffer)
__global__ __launch_bounds__(96) void k_bd(const float* __restrict__ dcre,
    const float* __restrict__ W1, const float* __restrict__ b1,
    const float* __restrict__ gam, const float* __restrict__ bet,
    const float* __restrict__ W2, const float* __restrict__ b2,
    float* __restrict__ bwout) {
  int bid = blockIdx.x;
  int b = bid / NG, gg = bid % NG;
  int tid = threadIdx.x;
  __shared__ float xm[ND];
  __shared__ float hs[NH];
  __shared__ float o3[3];
  const float* dc = dcre + (size_t)(b * NG + gg) * ND;
  for (int i = tid; i < ND; i += NH) xm[i] = dc[i] * (1.0f / NL);
  __syncthreads();
  float acc = b1[tid];
  for (int i = 0; i < ND; i++) acc += xm[i] * W1[i * NH + tid];
  hs[tid] = acc;
  __syncthreads();
  float s = 0, sq = 0;
  for (int i = 0; i < NH; i++) { float v = hs[i]; s += v; sq += v * v; }
  float m = s * (1.0f / NH), var = sq * (1.0f / NH) - m * m;
  float hn = fmaxf((acc - m) * rsqrtf(var + 1e-5f) * gam[tid] + bet[tid], 0.0f);
  __syncthreads();
  hs[tid] = hn;
  __syncthreads();
  if (tid < 3) {
    float o = b2[tid];
    for (int k = 0; k < NH; k++) o += hs[k] * W2[k * 3 + tid];
    o3[tid] = o;
  }
  __syncthreads();
  if (tid < 3) {
    float mx = fmaxf(o3[0], fmaxf(o3[1], o3[2]));
    float ssum = expf(o3[0] - mx) + expf(o3[1] - mx) + expf(o3[2] - mx);
    bwout[bid * 3 + tid] = expf(o3[tid] - mx) / ssum;
  }
}

// ---------------------------------------------------------------- mag/phase MLPs (fp16 MFMA) + modulate
// AROW=16 tile (LDS ~27.7KB -> 5 blocks/CU). Waves: br=wid>>1; pair duplicates GEMM1,
// splits GEMM2 chunks 2/2. Reads packed fp16 (mag,ph) MG[d][l]; writes packed (P,Q) in place.
#define AROW 16
#define APAD 390
__global__ __launch_bounds__(256, 5) void k_att8(
    unsigned int* __restrict__ MG,
    const __half* __restrict__ W1A,
    const __half* __restrict__ W2A,
    const float* __restrict__ mgb1, const float* __restrict__ mgg,
    const float* __restrict__ mgbe, const float* __restrict__ mgb2,
    const float* __restrict__ phb1, const float* __restrict__ phg,
    const float* __restrict__ phbe, const float* __restrict__ phb2,
    const float* __restrict__ bwp) {
  int bid = blockIdx.x;
  int bg = bid >> 6; int tile = bid & 63;
  int b = bg / NG, gg = bg % NG;
  int l0 = tile * AROW;                // storage-position base
  int tid = threadIdx.x;
  int lane = tid & 63, wid = tid >> 6;
  int r15 = lane & 15, kc = lane >> 4;
  int br = wid >> 1;                   // branch: 0=mag, 1=phase
  int ch0 = (wid & 1) * 2;             // this wave's GEMM2 chunk base (2 chunks)
  int wl = r15;                        // this lane's column (pos in tile)

  __shared__ short Am[AROW * APAD];    // stage1: fp16 mag; stage3: fp16 P
  __shared__ short Ap[AROW * APAD];    // stage1: fp16 phase; stage3: fp16 Q
  __shared__ short s_b1h[2][NH], s_gh[2][NH], s_beh[2][NH];
  __shared__ short s_b2h[2][ND];
  __shared__ float s_wm[AROW];

  size_t ib = ((size_t)b * NG * ND + gg * ND) * NL;

  // stage 1: issue ALL 6 loads upfront, then unpack
  uint4n mv[6];
#pragma unroll
  for (int u = 0; u < 6; u++) {
    int i = tid + u * 256;
    int d = i >> 2, lc = i & 3;
    mv[u] = *reinterpret_cast<const uint4n*>(&MG[ib + (size_t)d * NL + l0 + lc * 4]);
  }

  if (tid < NH) {
    s_b1h[0][tid] = hfx(mgb1[tid]); s_b1h[1][tid] = hfx(phb1[tid]);
    s_gh[0][tid]  = hfx(mgg[tid]);  s_gh[1][tid]  = hfx(phg[tid]);
    s_beh[0][tid] = hfx(mgbe[tid]); s_beh[1][tid] = hfx(phbe[tid]);
  }
  for (int i = tid; i < ND; i += 256) { s_b2h[0][i] = hfx(mgb2[i]); s_b2h[1][i] = hfx(phb2[i]); }
  if (tid < AROW) {   // band weight per storage position (true bin = rev4 of pos)
    int k = rev4_10(l0 + tid);
    int fr = (k <= 512) ? k : (1024 - k);
    int bwb = (b * NG + gg) * 3;
    s_wm[tid] = (fr <= 128) ? bwp[bwb] : ((fr <= 256) ? bwp[bwb + 1] : bwp[bwb + 2]);
  }

#pragma unroll
  for (int u = 0; u < 6; u++) {
    int i = tid + u * 256;
    int d = i >> 2, lc = i & 3;
#pragma unroll
    for (int j = 0; j < 4; j++) {
      int row = lc * 4 + j;
      unsigned w = mv[u][j];
      Am[row * APAD + d] = (short)(w & 0xffffu);
      Ap[row * APAD + d] = (short)(w >> 16);
    }
  }
  __syncthreads();

  // GEMM1 (branch; duplicated across the wave pair) -> LN -> relu -> fp16 packs
  unsigned pk[6][2];    // pk[f][p] = packed fp16 (h[f][2p], h[f][2p+1])
  {
    const short* Abuf = br ? Ap : Am;
    const __half* W1b = W1A + (size_t)br * 36864;
    f32x4 hacc[6];
#pragma unroll
    for (int f = 0; f < 6; f++) {
#pragma unroll
      for (int j = 0; j < 4; j++) hacc[f][j] = xhf(s_b1h[br][f * 16 + kc * 4 + j]);
    }
    for (int kk = 0; kk < 12; kk++) {
      half8n bx = *reinterpret_cast<const half8n*>(&Abuf[wl * APAD + kk * 32 + kc * 8]);
#pragma unroll
      for (int f = 0; f < 6; f++) {
        half8n aw = *reinterpret_cast<const half8n*>(
            (const void*)(W1b + (((size_t)kk * 6 + f) * 64 + lane) * 8));
        hacc[f] = __builtin_amdgcn_mfma_f32_16x16x32_f16(aw, bx, hacc[f], 0, 0, 0);
      }
    }
    float s = 0.f, sq = 0.f;
#pragma unroll
    for (int f = 0; f < 6; f++)
#pragma unroll
      for (int j = 0; j < 4; j++) { float v = hacc[f][j]; s += v; sq += v * v; }
    s += __shfl_xor(s, 16, 64); s += __shfl_xor(s, 32, 64);
    sq += __shfl_xor(sq, 16, 64); sq += __shfl_xor(sq, 32, 64);
    float mean = s * (1.0f / NH);
    float var = sq * (1.0f / NH) - mean * mean;
    float rstd = rsqrtf(var + 1e-5f);
#pragma unroll
    for (int f = 0; f < 6; f++) {
      float hn[4];
#pragma unroll
      for (int j = 0; j < 4; j++) {
        int m = f * 16 + kc * 4 + j;
        hn[j] = fmaxf((hacc[f][j] - mean) * rstd * xhf(s_gh[br][m]) + xhf(s_beh[br][m]), 0.0f);
      }
#pragma unroll
      for (int p = 0; p < 2; p++) {
        unsigned lo = (unsigned)(unsigned short)hfx(hn[2 * p]);
        unsigned hi = (unsigned)(unsigned short)hfx(hn[2 * p + 1]);
        pk[f][p] = lo | (hi << 16);
      }
    }
  }
  __syncthreads();   // all waves done reading Am/Ap before stash overwrites

  // in-register handoff: build GEMM2 B-frags bh[kk] via 4-lane-group shuffles.
  half8n bh[3];
  {
    int srcA = r15 + ((( 2 * kc )     & 3) << 4);
    int srcB = r15 + (((2 * kc + 1) & 3) << 4);
    int hiF = kc >> 1;
#pragma unroll
    for (int kk = 0; kk < 3; kk++) {
      int a0l = __shfl((int)pk[kk * 2][0], srcA, 64);
      int a0h = __shfl((int)pk[kk * 2 + 1][0], srcA, 64);
      int a1l = __shfl((int)pk[kk * 2][1], srcA, 64);
      int a1h = __shfl((int)pk[kk * 2 + 1][1], srcA, 64);
      int b0l = __shfl((int)pk[kk * 2][0], srcB, 64);
      int b0h = __shfl((int)pk[kk * 2 + 1][0], srcB, 64);
      int b1l = __shfl((int)pk[kk * 2][1], srcB, 64);
      int b1h = __shfl((int)pk[kk * 2 + 1][1], srcB, 64);
      int4 tv;
      tv.x = hiF ? a0h : a0l;
      tv.y = hiF ? a1h : a1l;
      tv.z = hiF ? b0h : b0l;
      tv.w = hiF ? b1h : b1l;
      bh[kk] = *reinterpret_cast<half8n*>(&tv);
    }
  }

  // GEMM2 (this wave: 2 of the 4 chunks): epilogue stashes finished P/Q (fp16) in LDS
  {
    const __half* W2b = W2A + (size_t)br * 36864;
    short* stash = br ? Ap : Am;
    float wm = s_wm[wl];
#pragma unroll
    for (int c2 = 0; c2 < 2; c2++) {
      int chunk = ch0 + c2;
      f32x4 aX[6];
#pragma unroll
      for (int f = 0; f < 6; f++) {
        int dbase = (chunk * 6 + f) * 16 + kc * 4;
#pragma unroll
        for (int j = 0; j < 4; j++) aX[f][j] = xhf(s_b2h[br][dbase + j]);
      }
#pragma unroll
      for (int kk = 0; kk < 3; kk++) {
#pragma unroll
        for (int f = 0; f < 6; f++) {
          int fg = chunk * 6 + f;
          half8n aw = *reinterpret_cast<const half8n*>(
              (const void*)(W2b + (((size_t)kk * 24 + fg) * 64 + lane) * 8));
          aX[f] = __builtin_amdgcn_mfma_f32_16x16x32_f16(aw, bh[kk], aX[f], 0, 0, 0);
        }
      }
#pragma unroll
      for (int f = 0; f < 6; f++) {
        int dbase = (chunk * 6 + f) * 16 + kc * 4;
        short4n q;
#pragma unroll
        for (int j = 0; j < 4; j++) {
          float base = xhf(stash[wl * APAD + dbase + j]);   // own mag or ph (fp16)
          float v;
          if (br) {                                          // Q = ph*wm + tanh(aX)
            v = base * wm + fast_tanh(aX[f][j]);
          } else {                                           // P = mag*wm*sigmoid(aX)
            v = base * wm * fast_sigmoid(aX[f][j]);
          }
          ((short*)&q)[j] = hfx(v);
        }
        *reinterpret_cast<short4n*>(&stash[wl * APAD + dbase]) = q;
      }
    }
  }
  __syncthreads();

  // final pass: pack (P,Q) and overwrite MG in place — pure data movement
#pragma unroll
  for (int u = 0; u < 6; u++) {
    int i = tid + u * 256;
    int d = i >> 2, lc = i & 3;
    size_t off = (size_t)d * NL + l0 + lc * 4;
    uint4n o;
#pragma unroll
    for (int j = 0; j < 4; j++) {
      int row = lc * 4 + j;
      unsigned P = (unsigned)(unsigned short)Am[row * APAD + d];
      unsigned Q = (unsigned)(unsigned short)Ap[row * APAD + d];
      o[j] = P | (Q << 16);
    }
    *reinterpret_cast<uint4n*>(&MG[ib + off]) = o;
  }
}

// ---------------------------------------------------------------- launch
extern "C" void kernel_launch(void* const* d_in, const int* in_sizes, int n_in,
                              void* d_out, int out_size, void* d_ws, size_t ws_size,
                              hipStream_t stream) {
  (void)in_sizes; (void)n_in; (void)out_size; (void)ws_size;
  const float* x     = (const float*)d_in[0];
  const float* mgW1  = (const float*)d_in[1];
  const float* mgb1  = (const float*)d_in[2];
  const float* mgg   = (const float*)d_in[3];
  const float* mgbe  = (const float*)d_in[4];
  const float* mgW2  = (const float*)d_in[5];
  const float* mgb2  = (const float*)d_in[6];
  const float* phW1  = (const float*)d_in[7];
  const float* phb1  = (const float*)d_in[8];
  const float* phg   = (const float*)d_in[9];
  const float* phbe  = (const float*)d_in[10];
  const float* phW2  = (const float*)d_in[11];
  const float* phb2  = (const float*)d_in[12];
  const float* bdW1  = (const float*)d_in[13];
  const float* bdb1  = (const float*)d_in[14];
  const float* bdg   = (const float*)d_in[15];
  const float* bdbe  = (const float*)d_in[16];
  const float* bdW2  = (const float*)d_in[17];
  const float* bdb2  = (const float*)d_in[18];
  const float* cgW1  = (const float*)d_in[19];
  const float* cgb1  = (const float*)d_in[20];
  const float* cgg   = (const float*)d_in[21];
  const float* cgbe  = (const float*)d_in[22];
  const float* cgW2  = (const float*)d_in[23];
  const float* cgb2  = (const float*)d_in[24];
  const float* convW = (const float*)d_in[25];
  const float* convB = (const float*)d_in[26];

  float* outp = (float*)d_out;
  __half* reh = (__half*)d_out;        // fp16 [d][l] conv-out lives in d_out rows 1..
  float* wsf  = (float*)d_ws;
  unsigned int* MG = (unsigned int*)wsf;
  __hip_bfloat16* gatedA = (__hip_bfloat16*)wsf;
  char* p = (char*)(wsf + (size_t)NB * NG * NL * ND);
  __hip_bfloat16* Wt2 = (__hip_bfloat16*)p;           p += (size_t)384 * 384 * 3 * 2;
  float* twid = (float*)p;                            p += 2048 * 4;   // 1024 complex
  float* bwp  = (float*)p;                            p += 512 * 4;
  float* dcre = (float*)p;                            p += (size_t)NB * NG * ND * 4;
  __half* W1A = (__half*)p;                           p += (size_t)2 * 36864 * 2;
  __half* W2A = (__half*)p;                           p += (size_t)2 * 36864 * 2;
  __hip_bfloat16* W1G = (__hip_bfloat16*)p;           p += (size_t)147456 * 2;

  k_prep<<<dim3(2932), dim3(256), 0, stream>>>(convW, x, mgW1, phW1, mgW2, phW2, cgW1,
                                               Wt2, twid, W1A, W2A, W1G, outp);
  k_gate2<<<dim3(NB * 64), dim3(256), 0, stream>>>(x, W1G, cgb1, cgg, cgbe, cgW2, cgb2, gatedA);
  k_conv_mfma<<<dim3(NB * NG * 8 * 3), dim3(256), 0, stream>>>(gatedA, Wt2, convB, reh);
  k_fft_fwd<<<dim3(NB * 288), dim3(256), 0, stream>>>(twid, reh, MG, dcre);
  k_bd<<<dim3(NB * NG), dim3(96), 0, stream>>>(dcre, bdW1, bdb1, bdg, bdbe, bdW2, bdb2, bwp);
  k_att8<<<dim3(NB * NG * 64), dim3(256), 0, stream>>>(MG,
      W1A, W2A, mgb1, mgg, mgbe, mgb2, phb1, phg, phbe, phb2, bwp);
  k_fft_inv<<<dim3(NB * 288), dim3(256), 0, stream>>>(twid, MG);
  k_tr<<<dim3(NB * NG * 16 * 6), dim3(256), 0, stream>>>((const __half*)MG, outp);
}

// Round 17
// 627.668 us; speedup vs baseline: 1.0053x; 1.0053x over previous
//
#include <hip/hip_runtime.h>
#include <hip/hip_bf16.h>
#include <hip/hip_fp16.h>
#include <math.h>

#define NB 32
#define NL 1024
#define NG 3
#define ND 384
#define NH 96
#define NDG 192
#define SEQR 3073   // 1 + G*L

typedef __attribute__((ext_vector_type(8))) short short8n;
typedef __attribute__((ext_vector_type(4))) short short4n;
typedef __attribute__((ext_vector_type(8))) _Float16 half8n;
typedef __attribute__((ext_vector_type(4))) float f32x4;
typedef __attribute__((ext_vector_type(4))) unsigned int uint4n;

__device__ __forceinline__ short bfx(float f) {
  __hip_bfloat16 h = __float2bfloat16(f);
  return *reinterpret_cast<short*>(&h);
}
__device__ __forceinline__ float xbf(short s) {
  __hip_bfloat16 h = *reinterpret_cast<__hip_bfloat16*>(&s);
  return __bfloat162float(h);
}
__device__ __forceinline__ short hfx(float f) {
  __half h = __float2half(f);
  return *reinterpret_cast<short*>(&h);
}
__device__ __forceinline__ float xhf(short s) {
  __half h = *reinterpret_cast<__half*>(&s);
  return __half2float(h);
}

// fast atan2, abs err <= ~1e-5 rad
__device__ __forceinline__ float fast_atan2f(float y, float x) {
  float ax = fabsf(x), ay = fabsf(y);
  float mx = fmaxf(ax, ay), mn = fminf(ax, ay);
  float r = (mx == 0.0f) ? 0.0f : __fdividef(mn, mx);
  float s = r * r;
  float p = fmaf(s, 0.0208351f, -0.0851330f);
  p = fmaf(s, p, 0.1801410f);
  p = fmaf(s, p, -0.3302995f);
  p = fmaf(s, p, 0.9998660f);
  p = r * p;
  float a = (ay > ax) ? (1.5707963267948966f - p) : p;
  a = (x < 0.0f) ? (3.14159265358979323846f - a) : a;
  return (y < 0.0f) ? -a : a;
}

__device__ __forceinline__ float fast_sigmoid(float x) {
  return __fdividef(1.0f, 1.0f + __expf(-x));
}
__device__ __forceinline__ float fast_tanh(float x) {
  return 1.0f - __fdividef(2.0f, 1.0f + __expf(2.0f * x));
}

// FFT LDS swizzles: break power-of-2 stride bank patterns
__device__ __forceinline__ int swzd(int p) { return p + (p >> 5); }  // data (max 1054)
__device__ __forceinline__ int swzt(int t) { return t + (t >> 4); }  // twiddle (max 814)

// base-4 digit reversal of a 10-bit index (5 digits)
__device__ __forceinline__ int rev4_10(int p) {
  unsigned q = (unsigned)p, r = 0;
#pragma unroll
  for (int i = 0; i < 5; i++) { r = (r << 2) | (q & 3); q >>= 2; }
  return (int)r;
}

// DIF radix-4 butterfly (fwd): in-place on A,B,C,D with twiddles w1,w2,w3
__device__ __forceinline__ void bfly_dif(float2& A, float2& B, float2& C, float2& D,
                                         float2 w1, float2 w2, float2 w3) {
  float t0r = A.x + C.x, t0i = A.y + C.y;
  float t1r = A.x - C.x, t1i = A.y - C.y;
  float t2r = B.x + D.x, t2i = B.y + D.y;
  float t3r = B.x - D.x, t3i = B.y - D.y;
  A = make_float2(t0r + t2r, t0i + t2i);
  float y1r = t1r + t3i, y1i = t1i - t3r;
  float y2r = t0r - t2r, y2i = t0i - t2i;
  float y3r = t1r - t3i, y3i = t1i + t3r;
  B = make_float2(y1r * w1.x - y1i * w1.y, y1r * w1.y + y1i * w1.x);
  C = make_float2(y2r * w2.x - y2i * w2.y, y2r * w2.y + y2i * w2.x);
  D = make_float2(y3r * w3.x - y3i * w3.y, y3r * w3.y + y3i * w3.x);
}

// DIT radix-4 butterfly (inv): conj-twiddle inputs B,C,D then combine
__device__ __forceinline__ void bfly_dit(float2& A, float2& B, float2& C, float2& D,
                                         float2 w1, float2 w2, float2 w3) {
  float bpr = B.x * w1.x + B.y * w1.y, bpi = B.y * w1.x - B.x * w1.y;
  float cpr = C.x * w2.x + C.y * w2.y, cpi = C.y * w2.x - C.x * w2.y;
  float dpr = D.x * w3.x + D.y * w3.y, dpi = D.y * w3.x - D.x * w3.y;
  float t0r = A.x + cpr, t0i = A.y + cpi;
  float t1r = A.x - cpr, t1i = A.y - cpi;
  float t2r = bpr + dpr, t2i = bpi + dpi;
  float er = bpr - dpr, ei = bpi - dpi;
  float t3r = -ei, t3i = er;
  A = make_float2(t0r + t2r, t0i + t2i);
  B = make_float2(t1r + t3r, t1i + t3i);
  C = make_float2(t0r - t2r, t0i - t2i);
  D = make_float2(t1r - t3r, t1i - t3i);
}

// DIT radix-4 butterfly, twiddle-free (e=0)
__device__ __forceinline__ void bfly_dit0(float2& A, float2& B, float2& C, float2& D) {
  float t0r = A.x + C.x, t0i = A.y + C.y;
  float t1r = A.x - C.x, t1i = A.y - C.y;
  float t2r = B.x + D.x, t2i = B.y + D.y;
  float er = B.x - D.x, ei = B.y - D.y;
  float t3r = -ei, t3i = er;
  A = make_float2(t0r + t2r, t0i + t2i);
  B = make_float2(t1r + t3r, t1i + t3i);
  C = make_float2(t0r - t2r, t0i - t2i);
  D = make_float2(t1r - t3r, t1i - t3i);
}

// ---------------------------------------------------------------- prep
__global__ __launch_bounds__(256) void k_prep(const float* __restrict__ convW,
                                              const float* __restrict__ x,
                                              const float* __restrict__ mgW1s,
                                              const float* __restrict__ phW1s,
                                              const float* __restrict__ mgW2s,
                                              const float* __restrict__ phW2s,
                                              const float* __restrict__ cgW1s,
                                              __hip_bfloat16* __restrict__ Wt2,
                                              float* __restrict__ twid,
                                              __half* __restrict__ W1Ao,
                                              __half* __restrict__ W2Ao,
                                              __hip_bfloat16* __restrict__ W1Go,
                                              float* __restrict__ outp) {
  int id = blockIdx.x * 256 + threadIdx.x;
  if (id < 384 * 384 * 3) {
    int i = id % 384; int rest = id / 384; int o = rest % 384; int kh = rest / 384;
    Wt2[id] = __float2bfloat16(convW[(o * 384 + i) * 3 + kh]);
    return;
  }
  int id2 = id - 384 * 384 * 3;
  if (id2 < 1024) {    // full-circle twiddle table (radix-4 needs up to W^765)
    float ang = -6.283185307179586f * (float)id2 / 1024.0f;
    float s, c; sincosf(ang, &s, &c);
    twid[2 * id2] = c; twid[2 * id2 + 1] = s;
    return;
  }
  int id3 = id2 - 1024;
  if (id3 < NB * ND) {
    int b = id3 / ND, d = id3 % ND;
    outp[(size_t)b * SEQR * ND + d] = x[(size_t)b * SEQR * ND + d];
    return;
  }
  int id4 = id3 - NB * ND;
  if (id4 < 2 * 36864) {   // W1A (fp16): [br][kk(12)][f(6)][lane(64)][8]
    int br = id4 / 36864, idx = id4 % 36864;
    int j = idx & 7, ln = (idx >> 3) & 63, rest = idx >> 9;
    int f = rest % 6, kk = rest / 6;
    int m = f * 16 + (ln & 15), k = kk * 32 + (ln >> 4) * 8 + j;
    const float* W = br ? phW1s : mgW1s;
    W1Ao[id4] = __float2half(W[k * NH + m]);
    return;
  }
  int id5 = id4 - 2 * 36864;
  if (id5 < 2 * 36864) {   // W2A (fp16): [br][kk(3)][f(24)][lane(64)][8]
    int br = id5 / 36864, idx = id5 % 36864;
    int j = idx & 7, ln = (idx >> 3) & 63, rest = idx >> 9;
    int f = rest % 24, kk = rest / 24;
    int d = f * 16 + (ln & 15), k = kk * 32 + (ln >> 4) * 8 + j;
    const float* W = br ? phW2s : mgW2s;
    W2Ao[id5] = __float2half(W[k * ND + d]);
    return;
  }
  int id6 = id5 - 2 * 36864;
  if (id6 < 147456) {      // W1G: [part(2)][kk(12)][f(12)][lane(64)][8]
    int j = id6 & 7, ln = (id6 >> 3) & 63, rest = id6 >> 9;
    int f = rest % 12, rest2 = rest / 12;
    int kk = rest2 % 12, part = rest2 / 12;
    int m = f * 16 + (ln & 15), k = part * 384 + kk * 32 + (ln >> 4) * 8 + j;
    W1Go[id6] = __float2bfloat16(cgW1s[k * NDG + m]);
  }
}

// ---------------------------------------------------------------- gate MLP via MFMA
__global__ __launch_bounds__(256) void k_gate2(const float* __restrict__ x,
    const __hip_bfloat16* __restrict__ W1G,
    const float* __restrict__ b1, const float* __restrict__ gam,
    const float* __restrict__ bet, const float* __restrict__ W2,
    const float* __restrict__ b2p,
    __hip_bfloat16* __restrict__ gatedA) {
  int bid = blockIdx.x;
  int b = bid >> 6; int l0 = (bid & 63) * 16;
  int tid = threadIdx.x;
  int lane = tid & 63, wid = tid >> 6;
  int r15 = lane & 15, kc = lane >> 4;

  __shared__ short xs[3][16][392];
  __shared__ short gs[16][392];
  __shared__ float hG[16][196];
  __shared__ float s_b1[NDG], s_g[NDG], s_be[NDG], s_w2[NDG];
  __shared__ float sgate[3][16];

  if (tid < NDG) {
    s_b1[tid] = b1[tid]; s_g[tid] = gam[tid];
    s_be[tid] = bet[tid]; s_w2[tid] = W2[tid];
  }
  for (int c = tid; c < 16 * 96; c += 256) {
    int l = c / 96, d4 = (c % 96) * 4;
    size_t base = ((size_t)b * SEQR + 1 + l0 + l) * ND + d4;
    float4 v0 = *reinterpret_cast<const float4*>(&x[base]);
    float4 v1 = *reinterpret_cast<const float4*>(&x[base + (size_t)NL * ND]);
    float4 v2 = *reinterpret_cast<const float4*>(&x[base + (size_t)2 * NL * ND]);
    short4n q0, q1, q2, qg;
    q0.x = bfx(v0.x); q0.y = bfx(v0.y); q0.z = bfx(v0.z); q0.w = bfx(v0.w);
    q1.x = bfx(v1.x); q1.y = bfx(v1.y); q1.z = bfx(v1.z); q1.w = bfx(v1.w);
    q2.x = bfx(v2.x); q2.y = bfx(v2.y); q2.z = bfx(v2.z); q2.w = bfx(v2.w);
    qg.x = bfx((v0.x + v1.x + v2.x) * (1.0f / 3.0f));
    qg.y = bfx((v0.y + v1.y + v2.y) * (1.0f / 3.0f));
    qg.z = bfx((v0.z + v1.z + v2.z) * (1.0f / 3.0f));
    qg.w = bfx((v0.w + v1.w + v2.w) * (1.0f / 3.0f));
    *reinterpret_cast<short4n*>(&xs[0][l][d4]) = q0;
    *reinterpret_cast<short4n*>(&xs[1][l][d4]) = q1;
    *reinterpret_cast<short4n*>(&xs[2][l][d4]) = q2;
    *reinterpret_cast<short4n*>(&gs[l][d4]) = qg;
  }
  __syncthreads();

  const short* bsrc = (wid == 3) ? &gs[0][0] : &xs[wid][0][0];
  const __hip_bfloat16* W1b = W1G + (size_t)(wid == 3 ? 1 : 0) * 73728;
  f32x4 hacc[12];
#pragma unroll
  for (int f = 0; f < 12; f++)
#pragma unroll
    for (int j = 0; j < 4; j++)
      hacc[f][j] = (wid == 3) ? 0.0f : s_b1[f * 16 + kc * 4 + j];
  for (int kk = 0; kk < 12; kk++) {
    short8n bx = *reinterpret_cast<const short8n*>(&bsrc[r15 * 392 + kk * 32 + kc * 8]);
#pragma unroll
    for (int f = 0; f < 12; f++) {
      short8n aw = *reinterpret_cast<const short8n*>(
          (const void*)(W1b + (((size_t)kk * 12 + f) * 64 + lane) * 8));
      hacc[f] = __builtin_amdgcn_mfma_f32_16x16x32_bf16(aw, bx, hacc[f], 0, 0, 0);
    }
  }
  if (wid == 3) {
#pragma unroll
    for (int f = 0; f < 12; f++)
#pragma unroll
      for (int j = 0; j < 4; j++)
        hG[r15][f * 16 + kc * 4 + j] = hacc[f][j];
  }
  __syncthreads();
  if (wid < 3) {
    float s = 0.f, sq = 0.f;
#pragma unroll
    for (int f = 0; f < 12; f++)
#pragma unroll
      for (int j = 0; j < 4; j++) {
        float v = hacc[f][j] + hG[r15][f * 16 + kc * 4 + j];
        hacc[f][j] = v; s += v; sq += v * v;
      }
    s += __shfl_xor(s, 16, 64); s += __shfl_xor(s, 32, 64);
    sq += __shfl_xor(sq, 16, 64); sq += __shfl_xor(sq, 32, 64);
    float mean = s * (1.0f / NDG);
    float var = sq * (1.0f / NDG) - mean * mean;
    float rstd = rsqrtf(var + 1e-5f);
    float dot = 0.f;
#pragma unroll
    for (int f = 0; f < 12; f++)
#pragma unroll
      for (int j = 0; j < 4; j++) {
        int m = f * 16 + kc * 4 + j;
        float hn = fmaxf((hacc[f][j] - mean) * rstd * s_g[m] + s_be[m], 0.0f);
        dot += hn * s_w2[m];
      }
    dot += __shfl_xor(dot, 16, 64); dot += __shfl_xor(dot, 32, 64);
    float gate = fast_sigmoid(dot + b2p[0]);
    if (lane < 16) sgate[wid][r15] = gate;
  }
  __syncthreads();
  if (wid < 3) {
    size_t obase = (((size_t)b * NG + wid) * NL + l0) * ND;
    for (int c = lane; c < 16 * 96; c += 64) {
      int l = c / 96, d4 = (c % 96) * 4;
      float gt = sgate[wid][l];
      short4n qx = *reinterpret_cast<const short4n*>(&xs[wid][l][d4]);
      short4n qg = *reinterpret_cast<const short4n*>(&gs[l][d4]);
      short4n qo;
#pragma unroll
      for (int j = 0; j < 4; j++) {
        float xv = xbf(((short*)&qx)[j]);
        float gv = xbf(((short*)&qg)[j]);
        ((short*)&qo)[j] = bfx(xv * gt + gv * (1.0f - gt));
      }
      *reinterpret_cast<short4n*>(&((short*)gatedA)[obase + (size_t)l * ND + d4]) = qo;
    }
  }
}

// ---------------------------------------------------------------- conv as bf16 MFMA GEMM
// output written TRANSPOSED as fp16: reh[(b*SEQR+1)*768 + (g*384+d)*NL + l]
#define BKC 64
__global__ __launch_bounds__(256) void k_conv_mfma(
    const __hip_bfloat16* __restrict__ Abuf,
    const __hip_bfloat16* __restrict__ Wt2,
    const float* __restrict__ cb,
    __half* __restrict__ reh) {
  int bid = blockIdx.x;
  int ct = bid % 3; int rest = bid / 3;
  int rt = rest % 8; int bg = rest / 8;
  int b = bg / NG, gg = bg % NG;
  int l0 = rt * 128;
  int n0 = ct * 128;
  int tid = threadIdx.x;
  int lane = tid & 63, wid = tid >> 6;
  int wr = wid >> 1, wc = wid & 1;
  int r15 = lane & 15, kc = lane >> 4;

  __shared__ short As[128 * BKC];
  __shared__ short Bs[128 * BKC];

  f32x4 acc[4][4];
#pragma unroll
  for (int m = 0; m < 4; m++)
#pragma unroll
    for (int n = 0; n < 4; n++) acc[m][n] = (f32x4){0.f, 0.f, 0.f, 0.f};

  for (int kh = 0; kh < 3; kh++) {
    int gs = gg + kh - 1;
    if (gs < 0 || gs >= NG) continue;
    const __hip_bfloat16* Ag = Abuf + (((size_t)b * NG + gs) * NL + l0) * ND;
    const __hip_bfloat16* Bg = Wt2 + ((size_t)kh * 384 + n0) * 384;
    for (int k0 = 0; k0 < 384; k0 += BKC) {
      __syncthreads();
#pragma unroll
      for (int p = 0; p < 4; p++) {
        int idx = p * 256 + tid;
        int row = idx >> 3, c = idx & 7;
        int csrc = c ^ (row & 7);
        __builtin_amdgcn_global_load_lds(
            (const __attribute__((address_space(1))) void*)(Ag + (size_t)row * ND + k0 + csrc * 8),
            (__attribute__((address_space(3))) void*)(&As[idx * 8]), 16, 0, 0);
      }
#pragma unroll
      for (int p = 0; p < 4; p++) {
        int idx = p * 256 + tid;
        int row = idx >> 3, c = idx & 7;
        int csrc = c ^ (row & 7);
        __builtin_amdgcn_global_load_lds(
            (const __attribute__((address_space(1))) void*)(Bg + (size_t)row * 384 + k0 + csrc * 8),
            (__attribute__((address_space(3))) void*)(&Bs[idx * 8]), 16, 0, 0);
      }
      __syncthreads();
#pragma unroll
      for (int ks = 0; ks < 2; ks++) {
        short8n af[4], bfr[4];
        int cdata = ks * 4 + kc;
#pragma unroll
        for (int m = 0; m < 4; m++) {
          int row = wr * 64 + m * 16 + r15;
          af[m] = *reinterpret_cast<const short8n*>(&As[row * 64 + (cdata ^ (row & 7)) * 8]);
          int col = wc * 64 + m * 16 + r15;
          bfr[m] = *reinterpret_cast<const short8n*>(&Bs[col * 64 + (cdata ^ (col & 7)) * 8]);
        }
#pragma unroll
        for (int m = 0; m < 4; m++)
#pragma unroll
          for (int n = 0; n < 4; n++)
            acc[m][n] = __builtin_amdgcn_mfma_f32_16x16x32_bf16(af[m], bfr[n], acc[m][n], 0, 0, 0);
      }
    }
  }
  // transposed fp16 epilogue: lane holds 4 consecutive l for fixed d -> ushort4 along l
  float cbv[4];
#pragma unroll
  for (int n = 0; n < 4; n++) cbv[n] = cb[n0 + wc * 64 + n * 16 + r15];
  size_t tbase = ((size_t)b * SEQR + 1) * (size_t)(ND * 2);   // half index of row 1
#pragma unroll
  for (int n = 0; n < 4; n++) {
    int drow = gg * ND + n0 + wc * 64 + n * 16 + r15;
#pragma unroll
    for (int m = 0; m < 4; m++) {
      int lcol = l0 + wr * 64 + m * 16 + kc * 4;
      short4n hv;
      hv.x = hfx(acc[m][n][0] + cbv[n]);
      hv.y = hfx(acc[m][n][1] + cbv[n]);
      hv.z = hfx(acc[m][n][2] + cbv[n]);
      hv.w = hfx(acc[m][n][3] + cbv[n]);
      *reinterpret_cast<short4n*>(&reh[tbase + (size_t)drow * NL + lcol]) = hv;
    }
  }
}

// ---------------------------------------------------------------- FFT fwd: radix-4 DIF fused 2-stage passes
// input fp16 re; output packed fp16 (mag,phase) into MG[d][l]; DC-bin re into dcre
__global__ __launch_bounds__(256) void k_fft_fwd(const float* __restrict__ twid,
                                                 const __half* __restrict__ reh,
                                                 unsigned int* __restrict__ MG,
                                                 float* __restrict__ dcre) {
  int bid = blockIdx.x;
  int b = bid / 288;
  int rloc = (bid % 288) * 4;
  size_t rbase = ((size_t)b * SEQR + 1) * (size_t)(ND * 2) + (size_t)rloc * NL;
  size_t ibase = ((size_t)b * NG * ND + rloc) * NL;
  int tid = threadIdx.x;
  __shared__ float2 sc[4][1056];
  __shared__ float2 stw[816];
  for (int t = tid; t < 768; t += 256)
    stw[swzt(t)] = make_float2(twid[2 * t], twid[2 * t + 1]);
  // batched load: all 8 loads in flight, then unpack
  {
    unsigned wv[8];
#pragma unroll
    for (int u = 0; u < 8; u++) {
      int idx = tid + u * 256;
      int line = idx >> 9, pp = idx & 511;
      wv[u] = *reinterpret_cast<const unsigned*>(&reh[rbase + (size_t)line * NL + pp * 2]);
    }
#pragma unroll
    for (int u = 0; u < 8; u++) {
      int idx = tid + u * 256;
      int line = idx >> 9, pp = idx & 511;
      sc[line][swzd(pp * 2)]     = make_float2(xhf((short)(wv[u] & 0xffffu)), 0.0f);
      sc[line][swzd(pp * 2 + 1)] = make_float2(xhf((short)(wv[u] >> 16)), 0.0f);
    }
  }
  __syncthreads();
  int line = tid >> 6;
  // ---- pass A: stages m=256 (s2=8), m=64 (s2=6)
  {
    int jjp = tid & 63;
    float2 X[4][4];
#pragma unroll
    for (int a = 0; a < 4; a++)
#pragma unroll
      for (int c = 0; c < 4; c++)
        X[a][c] = sc[line][swzd(a * 256 + c * 64 + jjp)];
#pragma unroll
    for (int c = 0; c < 4; c++) {       // stage m=256 over a; e = (c*64+jjp)
      int e = c * 64 + jjp;
      bfly_dif(X[0][c], X[1][c], X[2][c], X[3][c],
               stw[swzt(e)], stw[swzt(2 * e)], stw[swzt(3 * e)]);
    }
    {                                   // stage m=64 over c; e = jjp<<2
      int e = jjp << 2;
      float2 w1 = stw[swzt(e)], w2 = stw[swzt(2 * e)], w3 = stw[swzt(3 * e)];
#pragma unroll
      for (int a = 0; a < 4; a++)
        bfly_dif(X[a][0], X[a][1], X[a][2], X[a][3], w1, w2, w3);
    }
#pragma unroll
    for (int a = 0; a < 4; a++)
#pragma unroll
      for (int c = 0; c < 4; c++)
        sc[line][swzd(a * 256 + c * 64 + jjp)] = X[a][c];
  }
  __syncthreads();
  // ---- pass B: stages m=16 (s2=4), m=4 (s2=2)
  {
    int idx = tid & 63;
    int g = idx >> 2, jjp = idx & 3;
    int base = g * 64 + jjp;
    float2 X[4][4];
#pragma unroll
    for (int a = 0; a < 4; a++)
#pragma unroll
      for (int c = 0; c < 4; c++)
        X[a][c] = sc[line][swzd(base + a * 16 + c * 4)];
#pragma unroll
    for (int c = 0; c < 4; c++) {       // stage m=16 over a; e = (4c+jjp)<<4
      int e = (c * 4 + jjp) << 4;
      bfly_dif(X[0][c], X[1][c], X[2][c], X[3][c],
               stw[swzt(e)], stw[swzt(2 * e)], stw[swzt(3 * e)]);
    }
    {                                   // stage m=4 over c; e = jjp<<6
      int e = jjp << 6;
      float2 w1 = stw[swzt(e)], w2 = stw[swzt(2 * e)], w3 = stw[swzt(3 * e)];
#pragma unroll
      for (int a = 0; a < 4; a++)
        bfly_dif(X[a][0], X[a][1], X[a][2], X[a][3], w1, w2, w3);
    }
#pragma unroll
    for (int a = 0; a < 4; a++)
#pragma unroll
      for (int c = 0; c < 4; c++)
        sc[line][swzd(base + a * 16 + c * 4)] = X[a][c];
  }
  __syncthreads();
  // ---- pass C: stage m=1 (twiddle-free)
#pragma unroll
  for (int u = 0; u < 4; u++) {
    int p0 = tid * 4;
    float2 A = sc[u][swzd(p0)], B = sc[u][swzd(p0 + 1)];
    float2 C = sc[u][swzd(p0 + 2)], D = sc[u][swzd(p0 + 3)];
    float t0r = A.x + C.x, t0i = A.y + C.y;
    float t1r = A.x - C.x, t1i = A.y - C.y;
    float t2r = B.x + D.x, t2i = B.y + D.y;
    float t3r = B.x - D.x, t3i = B.y - D.y;
    sc[u][swzd(p0)]     = make_float2(t0r + t2r, t0i + t2i);
    sc[u][swzd(p0 + 1)] = make_float2(t1r + t3i, t1i - t3r);
    sc[u][swzd(p0 + 2)] = make_float2(t0r - t2r, t0i - t2i);
    sc[u][swzd(p0 + 3)] = make_float2(t1r - t3i, t1i + t3r);
  }
  __syncthreads();
  for (int idx = tid; idx < 4096; idx += 256) {
    int li = idx >> 10, pos = idx & 1023;
    float2 v = sc[li][swzd(pos)];
    unsigned mg = (unsigned)(unsigned short)hfx(sqrtf(v.x * v.x + v.y * v.y));
    unsigned ph = (unsigned)(unsigned short)hfx(fast_atan2f(v.y, v.x));
    MG[ibase + (size_t)li * NL + pos] = mg | (ph << 16);
    if (pos == 0) dcre[b * NG * ND + rloc + li] = v.x;   // DC bin (digit-rev(0)=0)
  }
}

// ---------------------------------------------------------------- FFT inv: radix-4 DIT fused 2-stage passes
// input: packed fp16 (P,Q) in MG; re=P*cos(Q), im=P*sin(Q); writes packed fp16 real in place
__global__ __launch_bounds__(256) void k_fft_inv(const float* __restrict__ twid,
                                                 unsigned int* __restrict__ MG) {
  int bid = blockIdx.x;
  int b = bid / 288;
  int rloc = (bid % 288) * 4;
  size_t ibase = ((size_t)b * NG * ND + rloc) * NL;
  int tid = threadIdx.x;
  __shared__ float2 sc[4][1056];
  __shared__ float2 stw[816];
  for (int t = tid; t < 768; t += 256)
    stw[swzt(t)] = make_float2(twid[2 * t], twid[2 * t + 1]);
  // batched load: two groups of 8 loads in flight
#pragma unroll
  for (int g = 0; g < 2; g++) {
    unsigned wv[8];
#pragma unroll
    for (int u = 0; u < 8; u++) {
      int idx = tid + (g * 8 + u) * 256;
      int lineu = idx >> 10, pos = idx & 1023;
      wv[u] = MG[ibase + (size_t)lineu * NL + pos];
    }
#pragma unroll
    for (int u = 0; u < 8; u++) {
      int idx = tid + (g * 8 + u) * 256;
      int lineu = idx >> 10, pos = idx & 1023;
      float P = xhf((short)(wv[u] & 0xffff));
      float Q = xhf((short)(wv[u] >> 16));
      sc[lineu][swzd(pos)] = make_float2(P * __cosf(Q), P * __sinf(Q));
    }
  }
  __syncthreads();
  int line = tid >> 6;
  // ---- pass A: stages m=1 (e=0), m=4
  {
    int G = tid & 63;
    int base = G * 16;
    float2 X[4][4];                      // X[q][r]
#pragma unroll
    for (int q = 0; q < 4; q++)
#pragma unroll
      for (int r = 0; r < 4; r++)
        X[q][r] = sc[line][swzd(base + q * 4 + r)];
#pragma unroll
    for (int q = 0; q < 4; q++)          // stage m=1 over r, twiddle-free
      bfly_dit0(X[q][0], X[q][1], X[q][2], X[q][3]);
#pragma unroll
    for (int r = 0; r < 4; r++) {        // stage m=4 over q; e = r<<6
      int e = r << 6;
      bfly_dit(X[0][r], X[1][r], X[2][r], X[3][r],
               stw[swzt(e)], stw[swzt(2 * e)], stw[swzt(3 * e)]);
    }
#pragma unroll
    for (int q = 0; q < 4; q++)
#pragma unroll
      for (int r = 0; r < 4; r++)
        sc[line][swzd(base + q * 4 + r)] = X[q][r];
  }
  __syncthreads();
  // ---- pass B: stages m=16, m=64
  {
    int idx = tid & 63;
    int G = idx >> 4, jj = idx & 15;
    int base = G * 256 + jj;
    float2 X[4][4];                      // X[k][u]
#pragma unroll
    for (int k = 0; k < 4; k++)
#pragma unroll
      for (int u = 0; u < 4; u++)
        X[k][u] = sc[line][swzd(base + u * 64 + k * 16)];
    {                                    // stage m=16 over k; e = jj<<4 (same all u)
      int e = jj << 4;
      float2 w1 = stw[swzt(e)], w2 = stw[swzt(2 * e)], w3 = stw[swzt(3 * e)];
#pragma unroll
      for (int u = 0; u < 4; u++)
        bfly_dit(X[0][u], X[1][u], X[2][u], X[3][u], w1, w2, w3);
    }
#pragma unroll
    for (int k = 0; k < 4; k++) {        // stage m=64 over u; e = (16k+jj)<<2
      int e = (k * 16 + jj) << 2;
      bfly_dit(X[k][0], X[k][1], X[k][2], X[k][3],
               stw[swzt(e)], stw[swzt(2 * e)], stw[swzt(3 * e)]);
    }
#pragma unroll
    for (int k = 0; k < 4; k++)
#pragma unroll
      for (int u = 0; u < 4; u++)
        sc[line][swzd(base + u * 64 + k * 16)] = X[k][u];
  }
  __syncthreads();
  // ---- pass C: stage m=256
#pragma unroll
  for (int u = 0; u < 4; u++) {
    int jj = tid;                        // 0..255
    int e = jj;
    float2 A = sc[u][swzd(jj)],       B = sc[u][swzd(jj + 256)];
    float2 C = sc[u][swzd(jj + 512)], D = sc[u][swzd(jj + 768)];
    bfly_dit(A, B, C, D, stw[swzt(e)], stw[swzt(2 * e)], stw[swzt(3 * e)]);
    sc[u][swzd(jj)] = A; sc[u][swzd(jj + 256)] = B;
    sc[u][swzd(jj + 512)] = C; sc[u][swzd(jj + 768)] = D;
  }
  __syncthreads();
  const float scf = 1.0f / 1024.0f;
  for (int idx = tid; idx < 2048; idx += 256) {
    int li = idx >> 9, pp = idx & 511;
    unsigned lo = (unsigned)(unsigned short)hfx(sc[li][swzd(2 * pp)].x * scf);
    unsigned hi = (unsigned)(unsigned short)hfx(sc[li][swzd(2 * pp + 1)].x * scf);
    MG[(ibase + (size_t)li * NL) / 2 + pp] = lo | (hi << 16);
  }
}

// ---------------------------------------------------------------- final transpose fp16 [d][l] -> fp32 [l][d]
__global__ __launch_bounds__(256) void k_tr(const __half* __restrict__ src,
                                            float* __restrict__ dst) {
  int bid = blockIdx.x;
  int dt = bid % 6; int r1 = bid / 6;
  int lt = r1 % 16; int r2 = r1 / 16;
  int gg = r2 % NG; int b = r2 / NG;
  int tid = threadIdx.x;
  __shared__ float T[64][67];
  size_t sbase = ((size_t)b * NG * ND + gg * ND + dt * 64) * NL + lt * 64;
  // batched loads
  {
    uint2 wv[4];
#pragma unroll
    for (int u = 0; u < 4; u++) {
      int c = tid + u * 256;
      int r = c >> 4, cc = c & 15;
      wv[u] = *reinterpret_cast<const uint2*>(&src[sbase + (size_t)r * NL + cc * 4]);
    }
#pragma unroll
    for (int u = 0; u < 4; u++) {
      int c = tid + u * 256;
      int r = c >> 4, cc = c & 15;
      T[r][cc * 4 + 0] = xhf((short)(wv[u].x & 0xffffu));
      T[r][cc * 4 + 1] = xhf((short)(wv[u].x >> 16));
      T[r][cc * 4 + 2] = xhf((short)(wv[u].y & 0xffffu));
      T[r][cc * 4 + 3] = xhf((short)(wv[u].y >> 16));
    }
  }
  __syncthreads();
  size_t dbase = ((size_t)b * SEQR + 1 + (size_t)gg * NL + lt * 64) * ND + dt * 64;
  for (int c = tid; c < 64 * 16; c += 256) {
    int r = c >> 4, cc = c & 15;
    float4 v = {T[cc * 4 + 0][r], T[cc * 4 + 1][r], T[cc * 4 + 2][r], T[cc * 4 + 3][r]};
    *reinterpret_cast<float4*>(&dst[dbase + (size_t)r * ND + cc * 4]) = v;
  }
}

// ---------------------------------------------------------------- band MLP (reads dcre side buffer)
__global__ __launch_bounds__(96) void k_bd(const float* __restrict__ dcre,
    const float* __restrict__ W1, const float* __restrict__ b1,
    const float* __restrict__ gam, const float* __restrict__ bet,
    const float* __restrict__ W2, const float* __restrict__ b2,
    float* __restrict__ bwout) {
  int bid = blockIdx.x;
  int b = bid / NG, gg = bid % NG;
  int tid = threadIdx.x;
  __shared__ float xm[ND];
  __shared__ float hs[NH];
  __shared__ float o3[3];
  const float* dc = dcre + (size_t)(b * NG + gg) * ND;
  for (int i = tid; i < ND; i += NH) xm[i] = dc[i] * (1.0f / NL);
  __syncthreads();
  float acc = b1[tid];
  for (int i = 0; i < ND; i++) acc += xm[i] * W1[i * NH + tid];
  hs[tid] = acc;
  __syncthreads();
  float s = 0, sq = 0;
  for (int i = 0; i < NH; i++) { float v = hs[i]; s += v; sq += v * v; }
  float m = s * (1.0f / NH), var = sq * (1.0f / NH) - m * m;
  float hn = fmaxf((acc - m) * rsqrtf(var + 1e-5f) * gam[tid] + bet[tid], 0.0f);
  __syncthreads();
  hs[tid] = hn;
  __syncthreads();
  if (tid < 3) {
    float o = b2[tid];
    for (int k = 0; k < NH; k++) o += hs[k] * W2[k * 3 + tid];
    o3[tid] = o;
  }
  __syncthreads();
  if (tid < 3) {
    float mx = fmaxf(o3[0], fmaxf(o3[1], o3[2]));
    float ssum = expf(o3[0] - mx) + expf(o3[1] - mx) + expf(o3[2] - mx);
    bwout[bid * 3 + tid] = expf(o3[tid] - mx) / ssum;
  }
}

// ---------------------------------------------------------------- mag/phase MLPs (fp16 MFMA) + modulate
// AROW=32 (proven R15 config); reads packed fp16 (mag,ph) MG[d][l]; writes packed (P,Q) in place.
#define AROW 32
#define APAD 390
__global__ __launch_bounds__(256, 3) void k_att7(
    unsigned int* __restrict__ MG,
    const __half* __restrict__ W1A,
    const __half* __restrict__ W2A,
    const float* __restrict__ mgb1, const float* __restrict__ mgg,
    const float* __restrict__ mgbe, const float* __restrict__ mgb2,
    const float* __restrict__ phb1, const float* __restrict__ phg,
    const float* __restrict__ phbe, const float* __restrict__ phb2,
    const float* __restrict__ bwp) {
  int bid = blockIdx.x;
  int bg = bid >> 5; int tile = bid & 31;
  int b = bg / NG, gg = bg % NG;
  int l0 = tile * AROW;                // storage-position base
  int tid = threadIdx.x;
  int lane = tid & 63, wid = tid >> 6;
  int r15 = lane & 15, kc = lane >> 4;
  int br = wid >> 1;                   // branch: 0=mag, 1=phase
  int wl = (wid & 1) * 16 + r15;       // this lane's column (pos in tile)

  __shared__ short Am[AROW * APAD];    // stage1: fp16 mag; stage3: fp16 P
  __shared__ short Ap[AROW * APAD];    // stage1: fp16 phase; stage3: fp16 Q
  __shared__ short s_b1h[2][NH], s_gh[2][NH], s_beh[2][NH];
  __shared__ short s_b2h[2][ND];
  __shared__ float s_wm[AROW];

  size_t ib = ((size_t)b * NG * ND + gg * ND) * NL;

  // stage 1: issue ALL 12 loads upfront, then unpack
  uint4n mv[12];
#pragma unroll
  for (int u = 0; u < 12; u++) {
    int i = tid + u * 256;
    int d = i >> 3, lc = i & 7;
    mv[u] = *reinterpret_cast<const uint4n*>(&MG[ib + (size_t)d * NL + l0 + lc * 4]);
  }

  if (tid < NH) {
    s_b1h[0][tid] = hfx(mgb1[tid]); s_b1h[1][tid] = hfx(phb1[tid]);
    s_gh[0][tid]  = hfx(mgg[tid]);  s_gh[1][tid]  = hfx(phg[tid]);
    s_beh[0][tid] = hfx(mgbe[tid]); s_beh[1][tid] = hfx(phbe[tid]);
  }
  for (int i = tid; i < ND; i += 256) { s_b2h[0][i] = hfx(mgb2[i]); s_b2h[1][i] = hfx(phb2[i]); }
  if (tid < AROW) {   // band weight per storage position (true bin = rev4 of pos)
    int k = rev4_10(l0 + tid);
    int fr = (k <= 512) ? k : (1024 - k);
    int bwb = (b * NG + gg) * 3;
    s_wm[tid] = (fr <= 128) ? bwp[bwb] : ((fr <= 256) ? bwp[bwb + 1] : bwp[bwb + 2]);
  }

#pragma unroll
  for (int u = 0; u < 12; u++) {
    int i = tid + u * 256;
    int d = i >> 3, lc = i & 7;
#pragma unroll
    for (int j = 0; j < 4; j++) {
      int row = lc * 4 + j;
      unsigned w = mv[u][j];
      Am[row * APAD + d] = (short)(w & 0xffffu);
      Ap[row * APAD + d] = (short)(w >> 16);
    }
  }
  __syncthreads();

  // GEMM1 (this wave's branch, fp16 MFMA) -> LN -> relu -> fp16 packs in registers
  unsigned pk[6][2];    // pk[f][p] = packed fp16 (h[f][2p], h[f][2p+1])
  {
    const short* Abuf = br ? Ap : Am;
    const __half* W1b = W1A + (size_t)br * 36864;
    f32x4 hacc[6];
#pragma unroll
    for (int f = 0; f < 6; f++) {
#pragma unroll
      for (int j = 0; j < 4; j++) hacc[f][j] = xhf(s_b1h[br][f * 16 + kc * 4 + j]);
    }
    __builtin_amdgcn_s_setprio(1);
    for (int kk = 0; kk < 12; kk++) {
      half8n bx = *reinterpret_cast<const half8n*>(&Abuf[wl * APAD + kk * 32 + kc * 8]);
#pragma unroll
      for (int f = 0; f < 6; f++) {
        half8n aw = *reinterpret_cast<const half8n*>(
            (const void*)(W1b + (((size_t)kk * 6 + f) * 64 + lane) * 8));
        hacc[f] = __builtin_amdgcn_mfma_f32_16x16x32_f16(aw, bx, hacc[f], 0, 0, 0);
      }
    }
    __builtin_amdgcn_s_setprio(0);
    float s = 0.f, sq = 0.f;
#pragma unroll
    for (int f = 0; f < 6; f++)
#pragma unroll
      for (int j = 0; j < 4; j++) { float v = hacc[f][j]; s += v; sq += v * v; }
    s += __shfl_xor(s, 16, 64); s += __shfl_xor(s, 32, 64);
    sq += __shfl_xor(sq, 16, 64); sq += __shfl_xor(sq, 32, 64);
    float mean = s * (1.0f / NH);
    float var = sq * (1.0f / NH) - mean * mean;
    float rstd = rsqrtf(var + 1e-5f);
#pragma unroll
    for (int f = 0; f < 6; f++) {
      float hn[4];
#pragma unroll
      for (int j = 0; j < 4; j++) {
        int m = f * 16 + kc * 4 + j;
        hn[j] = fmaxf((hacc[f][j] - mean) * rstd * xhf(s_gh[br][m]) + xhf(s_beh[br][m]), 0.0f);
      }
#pragma unroll
      for (int p = 0; p < 2; p++) {
        unsigned lo = (unsigned)(unsigned short)hfx(hn[2 * p]);
        unsigned hi = (unsigned)(unsigned short)hfx(hn[2 * p + 1]);
        pk[f][p] = lo | (hi << 16);
      }
    }
  }
  __syncthreads();   // all waves done reading Am/Ap before stash overwrites

  // in-register handoff: build GEMM2 B-frags bh[kk] via 4-lane-group shuffles.
  half8n bh[3];
  {
    int srcA = r15 + ((( 2 * kc )     & 3) << 4);
    int srcB = r15 + (((2 * kc + 1) & 3) << 4);
    int hiF = kc >> 1;
#pragma unroll
    for (int kk = 0; kk < 3; kk++) {
      int a0l = __shfl((int)pk[kk * 2][0], srcA, 64);
      int a0h = __shfl((int)pk[kk * 2 + 1][0], srcA, 64);
      int a1l = __shfl((int)pk[kk * 2][1], srcA, 64);
      int a1h = __shfl((int)pk[kk * 2 + 1][1], srcA, 64);
      int b0l = __shfl((int)pk[kk * 2][0], srcB, 64);
      int b0h = __shfl((int)pk[kk * 2 + 1][0], srcB, 64);
      int b1l = __shfl((int)pk[kk * 2][1], srcB, 64);
      int b1h = __shfl((int)pk[kk * 2 + 1][1], srcB, 64);
      int4 tv;
      tv.x = hiF ? a0h : a0l;
      tv.y = hiF ? a1h : a1l;
      tv.z = hiF ? b0h : b0l;
      tv.w = hiF ? b1h : b1l;
      bh[kk] = *reinterpret_cast<half8n*>(&tv);
    }
  }

  // GEMM2 (this wave's branch, fp16 MFMA): epilogue stashes finished P/Q (fp16) in LDS
  {
    const __half* W2b = W2A + (size_t)br * 36864;
    short* stash = br ? Ap : Am;
    float wm = s_wm[wl];
#pragma unroll
    for (int chunk = 0; chunk < 4; chunk++) {
      f32x4 aX[6];
#pragma unroll
      for (int f = 0; f < 6; f++) {
        int dbase = (chunk * 6 + f) * 16 + kc * 4;
#pragma unroll
        for (int j = 0; j < 4; j++) aX[f][j] = xhf(s_b2h[br][dbase + j]);
      }
      __builtin_amdgcn_s_setprio(1);
#pragma unroll
      for (int kk = 0; kk < 3; kk++) {
#pragma unroll
        for (int f = 0; f < 6; f++) {
          int fg = chunk * 6 + f;
          half8n aw = *reinterpret_cast<const half8n*>(
              (const void*)(W2b + (((size_t)kk * 24 + fg) * 64 + lane) * 8));
          aX[f] = __builtin_amdgcn_mfma_f32_16x16x32_f16(aw, bh[kk], aX[f], 0, 0, 0);
        }
      }
      __builtin_amdgcn_s_setprio(0);
#pragma unroll
      for (int f = 0; f < 6; f++) {
        int dbase = (chunk * 6 + f) * 16 + kc * 4;
        short4n q;
#pragma unroll
        for (int j = 0; j < 4; j++) {
          float base = xhf(stash[wl * APAD + dbase + j]);   // own mag or ph (fp16)
          float v;
          if (br) {                                          // Q = ph*wm + tanh(aX)
            v = base * wm + fast_tanh(aX[f][j]);
          } else {                                           // P = mag*wm*sigmoid(aX)
            v = base * wm * fast_sigmoid(aX[f][j]);
          }
          ((short*)&q)[j] = hfx(v);
        }
        *reinterpret_cast<short4n*>(&stash[wl * APAD + dbase]) = q;
      }
    }
  }
  __syncthreads();

  // final pass: pack (P,Q) and overwrite MG in place — pure data movement
  for (int u = 0; u < 12; u++) {
    int i = tid + u * 256;
    int d = i >> 3, lc = i & 7;
    size_t off = (size_t)d * NL + l0 + lc * 4;
    uint4n o;
#pragma unroll
    for (int j = 0; j < 4; j++) {
      int row = lc * 4 + j;
      unsigned P = (unsigned)(unsigned short)Am[row * APAD + d];
      unsigned Q = (unsigned)(unsigned short)Ap[row * APAD + d];
      o[j] = P | (Q << 16);
    }
    *reinterpret_cast<uint4n*>(&MG[ib + off]) = o;
  }
}

// ---------------------------------------------------------------- launch
extern "C" void kernel_launch(void* const* d_in, const int* in_sizes, int n_in,
                              void* d_out, int out_size, void* d_ws, size_t ws_size,
                              hipStream_t stream) {
  (void)in_sizes; (void)n_in; (void)out_size; (void)ws_size;
  const float* x     = (const float*)d_in[0];
  const float* mgW1  = (const float*)d_in[1];
  const float* mgb1  = (const float*)d_in[2];
  const float* mgg   = (const float*)d_in[3];
  const float* mgbe  = (const float*)d_in[4];
  const float* mgW2  = (const float*)d_in[5];
  const float* mgb2  = (const float*)d_in[6];
  const float* phW1  = (const float*)d_in[7];
  const float* phb1  = (const float*)d_in[8];
  const float* phg   = (const float*)d_in[9];
  const float* phbe  = (const float*)d_in[10];
  const float* phW2  = (const float*)d_in[11];
  const float* phb2  = (const float*)d_in[12];
  const float* bdW1  = (const float*)d_in[13];
  const float* bdb1  = (const float*)d_in[14];
  const float* bdg   = (const float*)d_in[15];
  const float* bdbe  = (const float*)d_in[16];
  const float* bdW2  = (const float*)d_in[17];
  const float* bdb2  = (const float*)d_in[18];
  const float* cgW1  = (const float*)d_in[19];
  const float* cgb1  = (const float*)d_in[20];
  const float* cgg   = (const float*)d_in[21];
  const float* cgbe  = (const float*)d_in[22];
  const float* cgW2  = (const float*)d_in[23];
  const float* cgb2  = (const float*)d_in[24];
  const float* convW = (const float*)d_in[25];
  const float* convB = (const float*)d_in[26];

  float* outp = (float*)d_out;
  __half* reh = (__half*)d_out;        // fp16 [d][l] conv-out lives in d_out rows 1..
  float* wsf  = (float*)d_ws;
  unsigned int* MG = (unsigned int*)wsf;
  __hip_bfloat16* gatedA = (__hip_bfloat16*)wsf;
  char* p = (char*)(wsf + (size_t)NB * NG * NL * ND);
  __hip_bfloat16* Wt2 = (__hip_bfloat16*)p;           p += (size_t)384 * 384 * 3 * 2;
  float* twid = (float*)p;                            p += 2048 * 4;   // 1024 complex
  float* bwp  = (float*)p;                            p += 512 * 4;
  float* dcre = (float*)p;                            p += (size_t)NB * NG * ND * 4;
  __half* W1A = (__half*)p;                           p += (size_t)2 * 36864 * 2;
  __half* W2A = (__half*)p;                           p += (size_t)2 * 36864 * 2;
  __hip_bfloat16* W1G = (__hip_bfloat16*)p;           p += (size_t)147456 * 2;

  k_prep<<<dim3(2932), dim3(256), 0, stream>>>(convW, x, mgW1, phW1, mgW2, phW2, cgW1,
                                               Wt2, twid, W1A, W2A, W1G, outp);
  k_gate2<<<dim3(NB * 64), dim3(256), 0, stream>>>(x, W1G, cgb1, cgg, cgbe, cgW2, cgb2, gatedA);
  k_conv_mfma<<<dim3(NB * NG * 8 * 3), dim3(256), 0, stream>>>(gatedA, Wt2, convB, reh);
  k_fft_fwd<<<dim3(NB * 288), dim3(256), 0, stream>>>(twid, reh, MG, dcre);
  k_bd<<<dim3(NB * NG), dim3(96), 0, stream>>>(dcre, bdW1, bdb1, bdg, bdbe, bdW2, bdb2, bwp);
  k_att7<<<dim3(NB * NG * 32), dim3(256), 0, stream>>>(MG,
      W1A, W2A, mgb1, mgg, mgbe, mgb2, phb1, phg, phbe, phb2, bwp);
  k_fft_inv<<<dim3(NB * 288), dim3(256), 0, stream>>>(twid, MG);
  k_tr<<<dim3(NB * NG * 16 * 6), dim3(256), 0, stream>>>((const __half*)MG, outp);
}

// Round 18
// 618.062 us; speedup vs baseline: 1.0209x; 1.0155x over previous
//
#include <hip/hip_runtime.h>
#include <hip/hip_bf16.h>
#include <hip/hip_fp16.h>
#include <math.h>

#define NB 32
#define NL 1024
#define NG 3
#define ND 384
#define NH 96
#define NDG 192
#define SEQR 3073   // 1 + G*L

typedef __attribute__((ext_vector_type(8))) short short8n;
typedef __attribute__((ext_vector_type(4))) short short4n;
typedef __attribute__((ext_vector_type(8))) _Float16 half8n;
typedef __attribute__((ext_vector_type(4))) float f32x4;
typedef __attribute__((ext_vector_type(4))) unsigned int uint4n;

__device__ __forceinline__ short bfx(float f) {
  __hip_bfloat16 h = __float2bfloat16(f);
  return *reinterpret_cast<short*>(&h);
}
__device__ __forceinline__ float xbf(short s) {
  __hip_bfloat16 h = *reinterpret_cast<__hip_bfloat16*>(&s);
  return __bfloat162float(h);
}
__device__ __forceinline__ short hfx(float f) {
  __half h = __float2half(f);
  return *reinterpret_cast<short*>(&h);
}
__device__ __forceinline__ float xhf(short s) {
  __half h = *reinterpret_cast<__half*>(&s);
  return __half2float(h);
}

// fast atan2, abs err <= ~1e-5 rad
__device__ __forceinline__ float fast_atan2f(float y, float x) {
  float ax = fabsf(x), ay = fabsf(y);
  float mx = fmaxf(ax, ay), mn = fminf(ax, ay);
  float r = (mx == 0.0f) ? 0.0f : __fdividef(mn, mx);
  float s = r * r;
  float p = fmaf(s, 0.0208351f, -0.0851330f);
  p = fmaf(s, p, 0.1801410f);
  p = fmaf(s, p, -0.3302995f);
  p = fmaf(s, p, 0.9998660f);
  p = r * p;
  float a = (ay > ax) ? (1.5707963267948966f - p) : p;
  a = (x < 0.0f) ? (3.14159265358979323846f - a) : a;
  return (y < 0.0f) ? -a : a;
}

__device__ __forceinline__ float fast_sigmoid(float x) {
  return __fdividef(1.0f, 1.0f + __expf(-x));
}
__device__ __forceinline__ float fast_tanh(float x) {
  return 1.0f - __fdividef(2.0f, 1.0f + __expf(2.0f * x));
}

// FFT LDS swizzles: break power-of-2 stride bank patterns
__device__ __forceinline__ int swzd(int p) { return p + (p >> 5); }  // data (max 1054)
__device__ __forceinline__ int swzt(int t) { return t + (t >> 4); }  // twiddle (max 814)

// base-4 digit reversal of a 10-bit index (5 digits)
__device__ __forceinline__ int rev4_10(int p) {
  unsigned q = (unsigned)p, r = 0;
#pragma unroll
  for (int i = 0; i < 5; i++) { r = (r << 2) | (q & 3); q >>= 2; }
  return (int)r;
}

// DIF radix-4 butterfly (fwd): in-place on A,B,C,D with twiddles w1,w2,w3
__device__ __forceinline__ void bfly_dif(float2& A, float2& B, float2& C, float2& D,
                                         float2 w1, float2 w2, float2 w3) {
  float t0r = A.x + C.x, t0i = A.y + C.y;
  float t1r = A.x - C.x, t1i = A.y - C.y;
  float t2r = B.x + D.x, t2i = B.y + D.y;
  float t3r = B.x - D.x, t3i = B.y - D.y;
  A = make_float2(t0r + t2r, t0i + t2i);
  float y1r = t1r + t3i, y1i = t1i - t3r;
  float y2r = t0r - t2r, y2i = t0i - t2i;
  float y3r = t1r - t3i, y3i = t1i + t3r;
  B = make_float2(y1r * w1.x - y1i * w1.y, y1r * w1.y + y1i * w1.x);
  C = make_float2(y2r * w2.x - y2i * w2.y, y2r * w2.y + y2i * w2.x);
  D = make_float2(y3r * w3.x - y3i * w3.y, y3r * w3.y + y3i * w3.x);
}

// DIT radix-4 butterfly (inv): conj-twiddle inputs B,C,D then combine
__device__ __forceinline__ void bfly_dit(float2& A, float2& B, float2& C, float2& D,
                                         float2 w1, float2 w2, float2 w3) {
  float bpr = B.x * w1.x + B.y * w1.y, bpi = B.y * w1.x - B.x * w1.y;
  float cpr = C.x * w2.x + C.y * w2.y, cpi = C.y * w2.x - C.x * w2.y;
  float dpr = D.x * w3.x + D.y * w3.y, dpi = D.y * w3.x - D.x * w3.y;
  float t0r = A.x + cpr, t0i = A.y + cpi;
  float t1r = A.x - cpr, t1i = A.y - cpi;
  float t2r = bpr + dpr, t2i = bpi + dpi;
  float er = bpr - dpr, ei = bpi - dpi;
  float t3r = -ei, t3i = er;
  A = make_float2(t0r + t2r, t0i + t2i);
  B = make_float2(t1r + t3r, t1i + t3i);
  C = make_float2(t0r - t2r, t0i - t2i);
  D = make_float2(t1r - t3r, t1i - t3i);
}

// DIT radix-4 butterfly, twiddle-free (e=0)
__device__ __forceinline__ void bfly_dit0(float2& A, float2& B, float2& C, float2& D) {
  float t0r = A.x + C.x, t0i = A.y + C.y;
  float t1r = A.x - C.x, t1i = A.y - C.y;
  float t2r = B.x + D.x, t2i = B.y + D.y;
  float er = B.x - D.x, ei = B.y - D.y;
  float t3r = -ei, t3i = er;
  A = make_float2(t0r + t2r, t0i + t2i);
  B = make_float2(t1r + t3r, t1i + t3i);
  C = make_float2(t0r - t2r, t0i - t2i);
  D = make_float2(t1r - t3r, t1i - t3i);
}

// ---------------------------------------------------------------- prep
__global__ __launch_bounds__(256) void k_prep(const float* __restrict__ convW,
                                              const float* __restrict__ x,
                                              const float* __restrict__ mgW1s,
                                              const float* __restrict__ phW1s,
                                              const float* __restrict__ mgW2s,
                                              const float* __restrict__ phW2s,
                                              const float* __restrict__ cgW1s,
                                              __hip_bfloat16* __restrict__ Wt2,
                                              float* __restrict__ twid,
                                              __half* __restrict__ W1Ao,
                                              __half* __restrict__ W2Ao,
                                              __hip_bfloat16* __restrict__ W1Go,
                                              float* __restrict__ outp) {
  int id = blockIdx.x * 256 + threadIdx.x;
  if (id < 384 * 384 * 3) {
    int i = id % 384; int rest = id / 384; int o = rest % 384; int kh = rest / 384;
    Wt2[id] = __float2bfloat16(convW[(o * 384 + i) * 3 + kh]);
    return;
  }
  int id2 = id - 384 * 384 * 3;
  if (id2 < 1024) {    // full-circle twiddle table (radix-4 needs up to W^765)
    float ang = -6.283185307179586f * (float)id2 / 1024.0f;
    float s, c; sincosf(ang, &s, &c);
    twid[2 * id2] = c; twid[2 * id2 + 1] = s;
    return;
  }
  int id3 = id2 - 1024;
  if (id3 < NB * ND) {
    int b = id3 / ND, d = id3 % ND;
    outp[(size_t)b * SEQR * ND + d] = x[(size_t)b * SEQR * ND + d];
    return;
  }
  int id4 = id3 - NB * ND;
  if (id4 < 2 * 36864) {   // W1A (fp16): [br][kk(12)][f(6)][lane(64)][8]
    int br = id4 / 36864, idx = id4 % 36864;
    int j = idx & 7, ln = (idx >> 3) & 63, rest = idx >> 9;
    int f = rest % 6, kk = rest / 6;
    int m = f * 16 + (ln & 15), k = kk * 32 + (ln >> 4) * 8 + j;
    const float* W = br ? phW1s : mgW1s;
    W1Ao[id4] = __float2half(W[k * NH + m]);
    return;
  }
  int id5 = id4 - 2 * 36864;
  if (id5 < 2 * 36864) {   // W2A (fp16): [br][kk(3)][f(24)][lane(64)][8]
    int br = id5 / 36864, idx = id5 % 36864;
    int j = idx & 7, ln = (idx >> 3) & 63, rest = idx >> 9;
    int f = rest % 24, kk = rest / 24;
    int d = f * 16 + (ln & 15), k = kk * 32 + (ln >> 4) * 8 + j;
    const float* W = br ? phW2s : mgW2s;
    W2Ao[id5] = __float2half(W[k * ND + d]);
    return;
  }
  int id6 = id5 - 2 * 36864;
  if (id6 < 147456) {      // W1G: [part(2)][kk(12)][f(12)][lane(64)][8]
    int j = id6 & 7, ln = (id6 >> 3) & 63, rest = id6 >> 9;
    int f = rest % 12, rest2 = rest / 12;
    int kk = rest2 % 12, part = rest2 / 12;
    int m = f * 16 + (ln & 15), k = part * 384 + kk * 32 + (ln >> 4) * 8 + j;
    W1Go[id6] = __float2bfloat16(cgW1s[k * NDG + m]);
  }
}

// ---------------------------------------------------------------- gate MLP via MFMA
__global__ __launch_bounds__(256) void k_gate2(const float* __restrict__ x,
    const __hip_bfloat16* __restrict__ W1G,
    const float* __restrict__ b1, const float* __restrict__ gam,
    const float* __restrict__ bet, const float* __restrict__ W2,
    const float* __restrict__ b2p,
    __hip_bfloat16* __restrict__ gatedA) {
  int bid = blockIdx.x;
  int b = bid >> 6; int l0 = (bid & 63) * 16;
  int tid = threadIdx.x;
  int lane = tid & 63, wid = tid >> 6;
  int r15 = lane & 15, kc = lane >> 4;

  __shared__ short xs[3][16][392];
  __shared__ short gs[16][392];
  __shared__ float hG[16][196];
  __shared__ float s_b1[NDG], s_g[NDG], s_be[NDG], s_w2[NDG];
  __shared__ float sgate[3][16];

  if (tid < NDG) {
    s_b1[tid] = b1[tid]; s_g[tid] = gam[tid];
    s_be[tid] = bet[tid]; s_w2[tid] = W2[tid];
  }
  for (int c = tid; c < 16 * 96; c += 256) {
    int l = c / 96, d4 = (c % 96) * 4;
    size_t base = ((size_t)b * SEQR + 1 + l0 + l) * ND + d4;
    float4 v0 = *reinterpret_cast<const float4*>(&x[base]);
    float4 v1 = *reinterpret_cast<const float4*>(&x[base + (size_t)NL * ND]);
    float4 v2 = *reinterpret_cast<const float4*>(&x[base + (size_t)2 * NL * ND]);
    short4n q0, q1, q2, qg;
    q0.x = bfx(v0.x); q0.y = bfx(v0.y); q0.z = bfx(v0.z); q0.w = bfx(v0.w);
    q1.x = bfx(v1.x); q1.y = bfx(v1.y); q1.z = bfx(v1.z); q1.w = bfx(v1.w);
    q2.x = bfx(v2.x); q2.y = bfx(v2.y); q2.z = bfx(v2.z); q2.w = bfx(v2.w);
    qg.x = bfx((v0.x + v1.x + v2.x) * (1.0f / 3.0f));
    qg.y = bfx((v0.y + v1.y + v2.y) * (1.0f / 3.0f));
    qg.z = bfx((v0.z + v1.z + v2.z) * (1.0f / 3.0f));
    qg.w = bfx((v0.w + v1.w + v2.w) * (1.0f / 3.0f));
    *reinterpret_cast<short4n*>(&xs[0][l][d4]) = q0;
    *reinterpret_cast<short4n*>(&xs[1][l][d4]) = q1;
    *reinterpret_cast<short4n*>(&xs[2][l][d4]) = q2;
    *reinterpret_cast<short4n*>(&gs[l][d4]) = qg;
  }
  __syncthreads();

  const short* bsrc = (wid == 3) ? &gs[0][0] : &xs[wid][0][0];
  const __hip_bfloat16* W1b = W1G + (size_t)(wid == 3 ? 1 : 0) * 73728;
  f32x4 hacc[12];
#pragma unroll
  for (int f = 0; f < 12; f++)
#pragma unroll
    for (int j = 0; j < 4; j++)
      hacc[f][j] = (wid == 3) ? 0.0f : s_b1[f * 16 + kc * 4 + j];
  for (int kk = 0; kk < 12; kk++) {
    short8n bx = *reinterpret_cast<const short8n*>(&bsrc[r15 * 392 + kk * 32 + kc * 8]);
#pragma unroll
    for (int f = 0; f < 12; f++) {
      short8n aw = *reinterpret_cast<const short8n*>(
          (const void*)(W1b + (((size_t)kk * 12 + f) * 64 + lane) * 8));
      hacc[f] = __builtin_amdgcn_mfma_f32_16x16x32_bf16(aw, bx, hacc[f], 0, 0, 0);
    }
  }
  if (wid == 3) {
#pragma unroll
    for (int f = 0; f < 12; f++)
#pragma unroll
      for (int j = 0; j < 4; j++)
        hG[r15][f * 16 + kc * 4 + j] = hacc[f][j];
  }
  __syncthreads();
  if (wid < 3) {
    float s = 0.f, sq = 0.f;
#pragma unroll
    for (int f = 0; f < 12; f++)
#pragma unroll
      for (int j = 0; j < 4; j++) {
        float v = hacc[f][j] + hG[r15][f * 16 + kc * 4 + j];
        hacc[f][j] = v; s += v; sq += v * v;
      }
    s += __shfl_xor(s, 16, 64); s += __shfl_xor(s, 32, 64);
    sq += __shfl_xor(sq, 16, 64); sq += __shfl_xor(sq, 32, 64);
    float mean = s * (1.0f / NDG);
    float var = sq * (1.0f / NDG) - mean * mean;
    float rstd = rsqrtf(var + 1e-5f);
    float dot = 0.f;
#pragma unroll
    for (int f = 0; f < 12; f++)
#pragma unroll
      for (int j = 0; j < 4; j++) {
        int m = f * 16 + kc * 4 + j;
        float hn = fmaxf((hacc[f][j] - mean) * rstd * s_g[m] + s_be[m], 0.0f);
        dot += hn * s_w2[m];
      }
    dot += __shfl_xor(dot, 16, 64); dot += __shfl_xor(dot, 32, 64);
    float gate = fast_sigmoid(dot + b2p[0]);
    if (lane < 16) sgate[wid][r15] = gate;
  }
  __syncthreads();
  if (wid < 3) {
    size_t obase = (((size_t)b * NG + wid) * NL + l0) * ND;
    for (int c = lane; c < 16 * 96; c += 64) {
      int l = c / 96, d4 = (c % 96) * 4;
      float gt = sgate[wid][l];
      short4n qx = *reinterpret_cast<const short4n*>(&xs[wid][l][d4]);
      short4n qg = *reinterpret_cast<const short4n*>(&gs[l][d4]);
      short4n qo;
#pragma unroll
      for (int j = 0; j < 4; j++) {
        float xv = xbf(((short*)&qx)[j]);
        float gv = xbf(((short*)&qg)[j]);
        ((short*)&qo)[j] = bfx(xv * gt + gv * (1.0f - gt));
      }
      *reinterpret_cast<short4n*>(&((short*)gatedA)[obase + (size_t)l * ND + d4]) = qo;
    }
  }
}

// ---------------------------------------------------------------- conv as bf16 MFMA GEMM
// output written TRANSPOSED as fp16: reh[(b*SEQR+1)*768 + (g*384+d)*NL + l]
#define BKC 64
__global__ __launch_bounds__(256) void k_conv_mfma(
    const __hip_bfloat16* __restrict__ Abuf,
    const __hip_bfloat16* __restrict__ Wt2,
    const float* __restrict__ cb,
    __half* __restrict__ reh) {
  int bid = blockIdx.x;
  int ct = bid % 3; int rest = bid / 3;
  int rt = rest % 8; int bg = rest / 8;
  int b = bg / NG, gg = bg % NG;
  int l0 = rt * 128;
  int n0 = ct * 128;
  int tid = threadIdx.x;
  int lane = tid & 63, wid = tid >> 6;
  int wr = wid >> 1, wc = wid & 1;
  int r15 = lane & 15, kc = lane >> 4;

  __shared__ short As[128 * BKC];
  __shared__ short Bs[128 * BKC];

  f32x4 acc[4][4];
#pragma unroll
  for (int m = 0; m < 4; m++)
#pragma unroll
    for (int n = 0; n < 4; n++) acc[m][n] = (f32x4){0.f, 0.f, 0.f, 0.f};

  for (int kh = 0; kh < 3; kh++) {
    int gs = gg + kh - 1;
    if (gs < 0 || gs >= NG) continue;
    const __hip_bfloat16* Ag = Abuf + (((size_t)b * NG + gs) * NL + l0) * ND;
    const __hip_bfloat16* Bg = Wt2 + ((size_t)kh * 384 + n0) * 384;
    for (int k0 = 0; k0 < 384; k0 += BKC) {
      __syncthreads();
#pragma unroll
      for (int p = 0; p < 4; p++) {
        int idx = p * 256 + tid;
        int row = idx >> 3, c = idx & 7;
        int csrc = c ^ (row & 7);
        __builtin_amdgcn_global_load_lds(
            (const __attribute__((address_space(1))) void*)(Ag + (size_t)row * ND + k0 + csrc * 8),
            (__attribute__((address_space(3))) void*)(&As[idx * 8]), 16, 0, 0);
      }
#pragma unroll
      for (int p = 0; p < 4; p++) {
        int idx = p * 256 + tid;
        int row = idx >> 3, c = idx & 7;
        int csrc = c ^ (row & 7);
        __builtin_amdgcn_global_load_lds(
            (const __attribute__((address_space(1))) void*)(Bg + (size_t)row * 384 + k0 + csrc * 8),
            (__attribute__((address_space(3))) void*)(&Bs[idx * 8]), 16, 0, 0);
      }
      __syncthreads();
#pragma unroll
      for (int ks = 0; ks < 2; ks++) {
        short8n af[4], bfr[4];
        int cdata = ks * 4 + kc;
#pragma unroll
        for (int m = 0; m < 4; m++) {
          int row = wr * 64 + m * 16 + r15;
          af[m] = *reinterpret_cast<const short8n*>(&As[row * 64 + (cdata ^ (row & 7)) * 8]);
          int col = wc * 64 + m * 16 + r15;
          bfr[m] = *reinterpret_cast<const short8n*>(&Bs[col * 64 + (cdata ^ (col & 7)) * 8]);
        }
#pragma unroll
        for (int m = 0; m < 4; m++)
#pragma unroll
          for (int n = 0; n < 4; n++)
            acc[m][n] = __builtin_amdgcn_mfma_f32_16x16x32_bf16(af[m], bfr[n], acc[m][n], 0, 0, 0);
      }
    }
  }
  // transposed fp16 epilogue: lane holds 4 consecutive l for fixed d -> ushort4 along l
  float cbv[4];
#pragma unroll
  for (int n = 0; n < 4; n++) cbv[n] = cb[n0 + wc * 64 + n * 16 + r15];
  size_t tbase = ((size_t)b * SEQR + 1) * (size_t)(ND * 2);   // half index of row 1
#pragma unroll
  for (int n = 0; n < 4; n++) {
    int drow = gg * ND + n0 + wc * 64 + n * 16 + r15;
#pragma unroll
    for (int m = 0; m < 4; m++) {
      int lcol = l0 + wr * 64 + m * 16 + kc * 4;
      short4n hv;
      hv.x = hfx(acc[m][n][0] + cbv[n]);
      hv.y = hfx(acc[m][n][1] + cbv[n]);
      hv.z = hfx(acc[m][n][2] + cbv[n]);
      hv.w = hfx(acc[m][n][3] + cbv[n]);
      *reinterpret_cast<short4n*>(&reh[tbase + (size_t)drow * NL + lcol]) = hv;
    }
  }
}

// ---------------------------------------------------------------- FFT fwd: radix-4 DIF fused 2-stage passes
// input fp16 re; output packed fp16 (mag,phase) into MG[d][l]; DC-bin re into dcre
__global__ __launch_bounds__(256) void k_fft_fwd(const float* __restrict__ twid,
                                                 const __half* __restrict__ reh,
                                                 unsigned int* __restrict__ MG,
                                                 float* __restrict__ dcre) {
  int bid = blockIdx.x;
  int b = bid / 288;
  int rloc = (bid % 288) * 4;
  size_t rbase = ((size_t)b * SEQR + 1) * (size_t)(ND * 2) + (size_t)rloc * NL;
  size_t ibase = ((size_t)b * NG * ND + rloc) * NL;
  int tid = threadIdx.x;
  __shared__ float2 sc[4][1056];
  __shared__ float2 stw[816];
  for (int t = tid; t < 768; t += 256)
    stw[swzt(t)] = make_float2(twid[2 * t], twid[2 * t + 1]);
  // batched load: all 8 loads in flight, then unpack
  {
    unsigned wv[8];
#pragma unroll
    for (int u = 0; u < 8; u++) {
      int idx = tid + u * 256;
      int line = idx >> 9, pp = idx & 511;
      wv[u] = *reinterpret_cast<const unsigned*>(&reh[rbase + (size_t)line * NL + pp * 2]);
    }
#pragma unroll
    for (int u = 0; u < 8; u++) {
      int idx = tid + u * 256;
      int line = idx >> 9, pp = idx & 511;
      sc[line][swzd(pp * 2)]     = make_float2(xhf((short)(wv[u] & 0xffffu)), 0.0f);
      sc[line][swzd(pp * 2 + 1)] = make_float2(xhf((short)(wv[u] >> 16)), 0.0f);
    }
  }
  __syncthreads();
  int line = tid >> 6;
  // ---- pass A: stages m=256 (s2=8), m=64 (s2=6)
  {
    int jjp = tid & 63;
    float2 X[4][4];
#pragma unroll
    for (int a = 0; a < 4; a++)
#pragma unroll
      for (int c = 0; c < 4; c++)
        X[a][c] = sc[line][swzd(a * 256 + c * 64 + jjp)];
#pragma unroll
    for (int c = 0; c < 4; c++) {       // stage m=256 over a; e = (c*64+jjp)
      int e = c * 64 + jjp;
      bfly_dif(X[0][c], X[1][c], X[2][c], X[3][c],
               stw[swzt(e)], stw[swzt(2 * e)], stw[swzt(3 * e)]);
    }
    {                                   // stage m=64 over c; e = jjp<<2
      int e = jjp << 2;
      float2 w1 = stw[swzt(e)], w2 = stw[swzt(2 * e)], w3 = stw[swzt(3 * e)];
#pragma unroll
      for (int a = 0; a < 4; a++)
        bfly_dif(X[a][0], X[a][1], X[a][2], X[a][3], w1, w2, w3);
    }
#pragma unroll
    for (int a = 0; a < 4; a++)
#pragma unroll
      for (int c = 0; c < 4; c++)
        sc[line][swzd(a * 256 + c * 64 + jjp)] = X[a][c];
  }
  __syncthreads();
  // ---- pass B: stages m=16 (s2=4), m=4 (s2=2)
  {
    int idx = tid & 63;
    int g = idx >> 2, jjp = idx & 3;
    int base = g * 64 + jjp;
    float2 X[4][4];
#pragma unroll
    for (int a = 0; a < 4; a++)
#pragma unroll
      for (int c = 0; c < 4; c++)
        X[a][c] = sc[line][swzd(base + a * 16 + c * 4)];
#pragma unroll
    for (int c = 0; c < 4; c++) {       // stage m=16 over a; e = (4c+jjp)<<4
      int e = (c * 4 + jjp) << 4;
      bfly_dif(X[0][c], X[1][c], X[2][c], X[3][c],
               stw[swzt(e)], stw[swzt(2 * e)], stw[swzt(3 * e)]);
    }
    {                                   // stage m=4 over c; e = jjp<<6
      int e = jjp << 6;
      float2 w1 = stw[swzt(e)], w2 = stw[swzt(2 * e)], w3 = stw[swzt(3 * e)];
#pragma unroll
      for (int a = 0; a < 4; a++)
        bfly_dif(X[a][0], X[a][1], X[a][2], X[a][3], w1, w2, w3);
    }
#pragma unroll
    for (int a = 0; a < 4; a++)
#pragma unroll
      for (int c = 0; c < 4; c++)
        sc[line][swzd(base + a * 16 + c * 4)] = X[a][c];
  }
  __syncthreads();
  // ---- pass C: stage m=1 (twiddle-free)
#pragma unroll
  for (int u = 0; u < 4; u++) {
    int p0 = tid * 4;
    float2 A = sc[u][swzd(p0)], B = sc[u][swzd(p0 + 1)];
    float2 C = sc[u][swzd(p0 + 2)], D = sc[u][swzd(p0 + 3)];
    float t0r = A.x + C.x, t0i = A.y + C.y;
    float t1r = A.x - C.x, t1i = A.y - C.y;
    float t2r = B.x + D.x, t2i = B.y + D.y;
    float t3r = B.x - D.x, t3i = B.y - D.y;
    sc[u][swzd(p0)]     = make_float2(t0r + t2r, t0i + t2i);
    sc[u][swzd(p0 + 1)] = make_float2(t1r + t3i, t1i - t3r);
    sc[u][swzd(p0 + 2)] = make_float2(t0r - t2r, t0i - t2i);
    sc[u][swzd(p0 + 3)] = make_float2(t1r - t3i, t1i + t3r);
  }
  __syncthreads();
  for (int idx = tid; idx < 4096; idx += 256) {
    int li = idx >> 10, pos = idx & 1023;
    float2 v = sc[li][swzd(pos)];
    unsigned mg = (unsigned)(unsigned short)hfx(sqrtf(v.x * v.x + v.y * v.y));
    unsigned ph = (unsigned)(unsigned short)hfx(fast_atan2f(v.y, v.x));
    MG[ibase + (size_t)li * NL + pos] = mg | (ph << 16);
    if (pos == 0) dcre[b * NG * ND + rloc + li] = v.x;   // DC bin (digit-rev(0)=0)
  }
}

// ---------------------------------------------------------------- FFT inv: radix-4 DIT fused 2-stage passes
// input: packed fp16 (P,Q) in MG; re=P*cos(Q), im=P*sin(Q); writes packed fp16 real in place
__global__ __launch_bounds__(256) void k_fft_inv(const float* __restrict__ twid,
                                                 unsigned int* __restrict__ MG) {
  int bid = blockIdx.x;
  int b = bid / 288;
  int rloc = (bid % 288) * 4;
  size_t ibase = ((size_t)b * NG * ND + rloc) * NL;
  int tid = threadIdx.x;
  __shared__ float2 sc[4][1056];
  __shared__ float2 stw[816];
  for (int t = tid; t < 768; t += 256)
    stw[swzt(t)] = make_float2(twid[2 * t], twid[2 * t + 1]);
  // batched load: two groups of 8 loads in flight
#pragma unroll
  for (int g = 0; g < 2; g++) {
    unsigned wv[8];
#pragma unroll
    for (int u = 0; u < 8; u++) {
      int idx = tid + (g * 8 + u) * 256;
      int lineu = idx >> 10, pos = idx & 1023;
      wv[u] = MG[ibase + (size_t)lineu * NL + pos];
    }
#pragma unroll
    for (int u = 0; u < 8; u++) {
      int idx = tid + (g * 8 + u) * 256;
      int lineu = idx >> 10, pos = idx & 1023;
      float P = xhf((short)(wv[u] & 0xffff));
      float Q = xhf((short)(wv[u] >> 16));
      sc[lineu][swzd(pos)] = make_float2(P * __cosf(Q), P * __sinf(Q));
    }
  }
  __syncthreads();
  int line = tid >> 6;
  // ---- pass A: stages m=1 (e=0), m=4
  {
    int G = tid & 63;
    int base = G * 16;
    float2 X[4][4];                      // X[q][r]
#pragma unroll
    for (int q = 0; q < 4; q++)
#pragma unroll
      for (int r = 0; r < 4; r++)
        X[q][r] = sc[line][swzd(base + q * 4 + r)];
#pragma unroll
    for (int q = 0; q < 4; q++)          // stage m=1 over r, twiddle-free
      bfly_dit0(X[q][0], X[q][1], X[q][2], X[q][3]);
#pragma unroll
    for (int r = 0; r < 4; r++) {        // stage m=4 over q; e = r<<6
      int e = r << 6;
      bfly_dit(X[0][r], X[1][r], X[2][r], X[3][r],
               stw[swzt(e)], stw[swzt(2 * e)], stw[swzt(3 * e)]);
    }
#pragma unroll
    for (int q = 0; q < 4; q++)
#pragma unroll
      for (int r = 0; r < 4; r++)
        sc[line][swzd(base + q * 4 + r)] = X[q][r];
  }
  __syncthreads();
  // ---- pass B: stages m=16, m=64
  {
    int idx = tid & 63;
    int G = idx >> 4, jj = idx & 15;
    int base = G * 256 + jj;
    float2 X[4][4];                      // X[k][u]
#pragma unroll
    for (int k = 0; k < 4; k++)
#pragma unroll
      for (int u = 0; u < 4; u++)
        X[k][u] = sc[line][swzd(base + u * 64 + k * 16)];
    {                                    // stage m=16 over k; e = jj<<4 (same all u)
      int e = jj << 4;
      float2 w1 = stw[swzt(e)], w2 = stw[swzt(2 * e)], w3 = stw[swzt(3 * e)];
#pragma unroll
      for (int u = 0; u < 4; u++)
        bfly_dit(X[0][u], X[1][u], X[2][u], X[3][u], w1, w2, w3);
    }
#pragma unroll
    for (int k = 0; k < 4; k++) {        // stage m=64 over u; e = (16k+jj)<<2
      int e = (k * 16 + jj) << 2;
      bfly_dit(X[k][0], X[k][1], X[k][2], X[k][3],
               stw[swzt(e)], stw[swzt(2 * e)], stw[swzt(3 * e)]);
    }
#pragma unroll
    for (int k = 0; k < 4; k++)
#pragma unroll
      for (int u = 0; u < 4; u++)
        sc[line][swzd(base + u * 64 + k * 16)] = X[k][u];
  }
  __syncthreads();
  // ---- pass C: stage m=256
#pragma unroll
  for (int u = 0; u < 4; u++) {
    int jj = tid;                        // 0..255
    int e = jj;
    float2 A = sc[u][swzd(jj)],       B = sc[u][swzd(jj + 256)];
    float2 C = sc[u][swzd(jj + 512)], D = sc[u][swzd(jj + 768)];
    bfly_dit(A, B, C, D, stw[swzt(e)], stw[swzt(2 * e)], stw[swzt(3 * e)]);
    sc[u][swzd(jj)] = A; sc[u][swzd(jj + 256)] = B;
    sc[u][swzd(jj + 512)] = C; sc[u][swzd(jj + 768)] = D;
  }
  __syncthreads();
  const float scf = 1.0f / 1024.0f;
  for (int idx = tid; idx < 2048; idx += 256) {
    int li = idx >> 9, pp = idx & 511;
    unsigned lo = (unsigned)(unsigned short)hfx(sc[li][swzd(2 * pp)].x * scf);
    unsigned hi = (unsigned)(unsigned short)hfx(sc[li][swzd(2 * pp + 1)].x * scf);
    MG[(ibase + (size_t)li * NL) / 2 + pp] = lo | (hi << 16);
  }
}

// ---------------------------------------------------------------- final transpose fp16 [d][l] -> fp32 [l][d]
__global__ __launch_bounds__(256) void k_tr(const __half* __restrict__ src,
                                            float* __restrict__ dst) {
  int bid = blockIdx.x;
  int dt = bid % 6; int r1 = bid / 6;
  int lt = r1 % 16; int r2 = r1 / 16;
  int gg = r2 % NG; int b = r2 / NG;
  int tid = threadIdx.x;
  __shared__ float T[64][67];
  size_t sbase = ((size_t)b * NG * ND + gg * ND + dt * 64) * NL + lt * 64;
  // batched loads
  {
    uint2 wv[4];
#pragma unroll
    for (int u = 0; u < 4; u++) {
      int c = tid + u * 256;
      int r = c >> 4, cc = c & 15;
      wv[u] = *reinterpret_cast<const uint2*>(&src[sbase + (size_t)r * NL + cc * 4]);
    }
#pragma unroll
    for (int u = 0; u < 4; u++) {
      int c = tid + u * 256;
      int r = c >> 4, cc = c & 15;
      T[r][cc * 4 + 0] = xhf((short)(wv[u].x & 0xffffu));
      T[r][cc * 4 + 1] = xhf((short)(wv[u].x >> 16));
      T[r][cc * 4 + 2] = xhf((short)(wv[u].y & 0xffffu));
      T[r][cc * 4 + 3] = xhf((short)(wv[u].y >> 16));
    }
  }
  __syncthreads();
  size_t dbase = ((size_t)b * SEQR + 1 + (size_t)gg * NL + lt * 64) * ND + dt * 64;
  for (int c = tid; c < 64 * 16; c += 256) {
    int r = c >> 4, cc = c & 15;
    float4 v = {T[cc * 4 + 0][r], T[cc * 4 + 1][r], T[cc * 4 + 2][r], T[cc * 4 + 3][r]};
    *reinterpret_cast<float4*>(&dst[dbase + (size_t)r * ND + cc * 4]) = v;
  }
}

// ---------------------------------------------------------------- band MLP (reads dcre side buffer)
__global__ __launch_bounds__(96) void k_bd(const float* __restrict__ dcre,
    const float* __restrict__ W1, const float* __restrict__ b1,
    const float* __restrict__ gam, const float* __restrict__ bet,
    const float* __restrict__ W2, const float* __restrict__ b2,
    float* __restrict__ bwout) {
  int bid = blockIdx.x;
  int b = bid / NG, gg = bid % NG;
  int tid = threadIdx.x;
  __shared__ float xm[ND];
  __shared__ float hs[NH];
  __shared__ float o3[3];
  const float* dc = dcre + (size_t)(b * NG + gg) * ND;
  for (int i = tid; i < ND; i += NH) xm[i] = dc[i] * (1.0f / NL);
  __syncthreads();
  float acc = b1[tid];
  for (int i = 0; i < ND; i++) acc += xm[i] * W1[i * NH + tid];
  hs[tid] = acc;
  __syncthreads();
  float s = 0, sq = 0;
  for (int i = 0; i < NH; i++) { float v = hs[i]; s += v; sq += v * v; }
  float m = s * (1.0f / NH), var = sq * (1.0f / NH) - m * m;
  float hn = fmaxf((acc - m) * rsqrtf(var + 1e-5f) * gam[tid] + bet[tid], 0.0f);
  __syncthreads();
  hs[tid] = hn;
  __syncthreads();
  if (tid < 3) {
    float o = b2[tid];
    for (int k = 0; k < NH; k++) o += hs[k] * W2[k * 3 + tid];
    o3[tid] = o;
  }
  __syncthreads();
  if (tid < 3) {
    float mx = fmaxf(o3[0], fmaxf(o3[1], o3[2]));
    float ssum = expf(o3[0] - mx) + expf(o3[1] - mx) + expf(o3[2] - mx);
    bwout[bid * 3 + tid] = expf(o3[tid] - mx) / ssum;
  }
}

// ---------------------------------------------------------------- mag/phase MLPs (fp16 MFMA) + modulate
// AROW=32 (proven R15 config); reads packed fp16 (mag,ph) MG[d][l]; writes packed (P,Q) in place.
#define AROW 32
#define APAD 390
__global__ __launch_bounds__(256, 3) void k_att7(
    unsigned int* __restrict__ MG,
    const __half* __restrict__ W1A,
    const __half* __restrict__ W2A,
    const float* __restrict__ mgb1, const float* __restrict__ mgg,
    const float* __restrict__ mgbe, const float* __restrict__ mgb2,
    const float* __restrict__ phb1, const float* __restrict__ phg,
    const float* __restrict__ phbe, const float* __restrict__ phb2,
    const float* __restrict__ bwp) {
  int bid = blockIdx.x;
  int bg = bid >> 5; int tile = bid & 31;
  int b = bg / NG, gg = bg % NG;
  int l0 = tile * AROW;                // storage-position base
  int tid = threadIdx.x;
  int lane = tid & 63, wid = tid >> 6;
  int r15 = lane & 15, kc = lane >> 4;
  int br = wid >> 1;                   // branch: 0=mag, 1=phase
  int wl = (wid & 1) * 16 + r15;       // this lane's column (pos in tile)

  __shared__ short Am[AROW * APAD];    // stage1: fp16 mag; stage3: fp16 P
  __shared__ short Ap[AROW * APAD];    // stage1: fp16 phase; stage3: fp16 Q
  __shared__ short s_b1h[2][NH], s_gh[2][NH], s_beh[2][NH];
  __shared__ short s_b2h[2][ND];
  __shared__ float s_wm[AROW];

  size_t ib = ((size_t)b * NG * ND + gg * ND) * NL;

  // stage 1: issue ALL 12 loads upfront, then unpack
  uint4n mv[12];
#pragma unroll
  for (int u = 0; u < 12; u++) {
    int i = tid + u * 256;
    int d = i >> 3, lc = i & 7;
    mv[u] = *reinterpret_cast<const uint4n*>(&MG[ib + (size_t)d * NL + l0 + lc * 4]);
  }

  if (tid < NH) {
    s_b1h[0][tid] = hfx(mgb1[tid]); s_b1h[1][tid] = hfx(phb1[tid]);
    s_gh[0][tid]  = hfx(mgg[tid]);  s_gh[1][tid]  = hfx(phg[tid]);
    s_beh[0][tid] = hfx(mgbe[tid]); s_beh[1][tid] = hfx(phbe[tid]);
  }
  for (int i = tid; i < ND; i += 256) { s_b2h[0][i] = hfx(mgb2[i]); s_b2h[1][i] = hfx(phb2[i]); }
  if (tid < AROW) {   // band weight per storage position (true bin = rev4 of pos)
    int k = rev4_10(l0 + tid);
    int fr = (k <= 512) ? k : (1024 - k);
    int bwb = (b * NG + gg) * 3;
    s_wm[tid] = (fr <= 128) ? bwp[bwb] : ((fr <= 256) ? bwp[bwb + 1] : bwp[bwb + 2]);
  }

#pragma unroll
  for (int u = 0; u < 12; u++) {
    int i = tid + u * 256;
    int d = i >> 3, lc = i & 7;
#pragma unroll
    for (int j = 0; j < 4; j++) {
      int row = lc * 4 + j;
      unsigned w = mv[u][j];
      Am[row * APAD + d] = (short)(w & 0xffffu);
      Ap[row * APAD + d] = (short)(w >> 16);
    }
  }
  __syncthreads();

  // GEMM1 (this wave's branch, fp16 MFMA) -> LN -> relu -> fp16 packs in registers
  unsigned pk[6][2];    // pk[f][p] = packed fp16 (h[f][2p], h[f][2p+1])
  {
    const short* Abuf = br ? Ap : Am;
    const __half* W1b = W1A + (size_t)br * 36864;
    f32x4 hacc[6];
#pragma unroll
    for (int f = 0; f < 6; f++) {
#pragma unroll
      for (int j = 0; j < 4; j++) hacc[f][j] = xhf(s_b1h[br][f * 16 + kc * 4 + j]);
    }
    for (int kk = 0; kk < 12; kk++) {
      half8n bx = *reinterpret_cast<const half8n*>(&Abuf[wl * APAD + kk * 32 + kc * 8]);
#pragma unroll
      for (int f = 0; f < 6; f++) {
        half8n aw = *reinterpret_cast<const half8n*>(
            (const void*)(W1b + (((size_t)kk * 6 + f) * 64 + lane) * 8));
        hacc[f] = __builtin_amdgcn_mfma_f32_16x16x32_f16(aw, bx, hacc[f], 0, 0, 0);
      }
    }
    float s = 0.f, sq = 0.f;
#pragma unroll
    for (int f = 0; f < 6; f++)
#pragma unroll
      for (int j = 0; j < 4; j++) { float v = hacc[f][j]; s += v; sq += v * v; }
    s += __shfl_xor(s, 16, 64); s += __shfl_xor(s, 32, 64);
    sq += __shfl_xor(sq, 16, 64); sq += __shfl_xor(sq, 32, 64);
    float mean = s * (1.0f / NH);
    float var = sq * (1.0f / NH) - mean * mean;
    float rstd = rsqrtf(var + 1e-5f);
#pragma unroll
    for (int f = 0; f < 6; f++) {
      float hn[4];
#pragma unroll
      for (int j = 0; j < 4; j++) {
        int m = f * 16 + kc * 4 + j;
        hn[j] = fmaxf((hacc[f][j] - mean) * rstd * xhf(s_gh[br][m]) + xhf(s_beh[br][m]), 0.0f);
      }
#pragma unroll
      for (int p = 0; p < 2; p++) {
        unsigned lo = (unsigned)(unsigned short)hfx(hn[2 * p]);
        unsigned hi = (unsigned)(unsigned short)hfx(hn[2 * p + 1]);
        pk[f][p] = lo | (hi << 16);
      }
    }
  }
  __syncthreads();   // all waves done reading Am/Ap before stash overwrites

  // in-register handoff: build GEMM2 B-frags bh[kk] via 4-lane-group shuffles.
  half8n bh[3];
  {
    int srcA = r15 + ((( 2 * kc )     & 3) << 4);
    int srcB = r15 + (((2 * kc + 1) & 3) << 4);
    int hiF = kc >> 1;
#pragma unroll
    for (int kk = 0; kk < 3; kk++) {
      int a0l = __shfl((int)pk[kk * 2][0], srcA, 64);
      int a0h = __shfl((int)pk[kk * 2 + 1][0], srcA, 64);
      int a1l = __shfl((int)pk[kk * 2][1], srcA, 64);
      int a1h = __shfl((int)pk[kk * 2 + 1][1], srcA, 64);
      int b0l = __shfl((int)pk[kk * 2][0], srcB, 64);
      int b0h = __shfl((int)pk[kk * 2 + 1][0], srcB, 64);
      int b1l = __shfl((int)pk[kk * 2][1], srcB, 64);
      int b1h = __shfl((int)pk[kk * 2 + 1][1], srcB, 64);
      int4 tv;
      tv.x = hiF ? a0h : a0l;
      tv.y = hiF ? a1h : a1l;
      tv.z = hiF ? b0h : b0l;
      tv.w = hiF ? b1h : b1l;
      bh[kk] = *reinterpret_cast<half8n*>(&tv);
    }
  }

  // GEMM2 (this wave's branch, fp16 MFMA): epilogue stashes finished P/Q (fp16) in LDS
  {
    const __half* W2b = W2A + (size_t)br * 36864;
    short* stash = br ? Ap : Am;
    float wm = s_wm[wl];
#pragma unroll
    for (int chunk = 0; chunk < 4; chunk++) {
      f32x4 aX[6];
#pragma unroll
      for (int f = 0; f < 6; f++) {
        int dbase = (chunk * 6 + f) * 16 + kc * 4;
#pragma unroll
        for (int j = 0; j < 4; j++) aX[f][j] = xhf(s_b2h[br][dbase + j]);
      }
#pragma unroll
      for (int kk = 0; kk < 3; kk++) {
#pragma unroll
        for (int f = 0; f < 6; f++) {
          int fg = chunk * 6 + f;
          half8n aw = *reinterpret_cast<const half8n*>(
              (const void*)(W2b + (((size_t)kk * 24 + fg) * 64 + lane) * 8));
          aX[f] = __builtin_amdgcn_mfma_f32_16x16x32_f16(aw, bh[kk], aX[f], 0, 0, 0);
        }
      }
#pragma unroll
      for (int f = 0; f < 6; f++) {
        int dbase = (chunk * 6 + f) * 16 + kc * 4;
        short4n q;
#pragma unroll
        for (int j = 0; j < 4; j++) {
          float base = xhf(stash[wl * APAD + dbase + j]);   // own mag or ph (fp16)
          float v;
          if (br) {                                          // Q = ph*wm + tanh(aX)
            v = base * wm + fast_tanh(aX[f][j]);
          } else {                                           // P = mag*wm*sigmoid(aX)
            v = base * wm * fast_sigmoid(aX[f][j]);
          }
          ((short*)&q)[j] = hfx(v);
        }
        *reinterpret_cast<short4n*>(&stash[wl * APAD + dbase]) = q;
      }
    }
  }
  __syncthreads();

  // final pass: pack (P,Q) and overwrite MG in place — pure data movement
  for (int u = 0; u < 12; u++) {
    int i = tid + u * 256;
    int d = i >> 3, lc = i & 7;
    size_t off = (size_t)d * NL + l0 + lc * 4;
    uint4n o;
#pragma unroll
    for (int j = 0; j < 4; j++) {
      int row = lc * 4 + j;
      unsigned P = (unsigned)(unsigned short)Am[row * APAD + d];
      unsigned Q = (unsigned)(unsigned short)Ap[row * APAD + d];
      o[j] = P | (Q << 16);
    }
    *reinterpret_cast<uint4n*>(&MG[ib + off]) = o;
  }
}

// ---------------------------------------------------------------- launch
extern "C" void kernel_launch(void* const* d_in, const int* in_sizes, int n_in,
                              void* d_out, int out_size, void* d_ws, size_t ws_size,
                              hipStream_t stream) {
  (void)in_sizes; (void)n_in; (void)out_size; (void)ws_size;
  const float* x     = (const float*)d_in[0];
  const float* mgW1  = (const float*)d_in[1];
  const float* mgb1  = (const float*)d_in[2];
  const float* mgg   = (const float*)d_in[3];
  const float* mgbe  = (const float*)d_in[4];
  const float* mgW2  = (const float*)d_in[5];
  const float* mgb2  = (const float*)d_in[6];
  const float* phW1  = (const float*)d_in[7];
  const float* phb1  = (const float*)d_in[8];
  const float* phg   = (const float*)d_in[9];
  const float* phbe  = (const float*)d_in[10];
  const float* phW2  = (const float*)d_in[11];
  const float* phb2  = (const float*)d_in[12];
  const float* bdW1  = (const float*)d_in[13];
  const float* bdb1  = (const float*)d_in[14];
  const float* bdg   = (const float*)d_in[15];
  const float* bdbe  = (const float*)d_in[16];
  const float* bdW2  = (const float*)d_in[17];
  const float* bdb2  = (const float*)d_in[18];
  const float* cgW1  = (const float*)d_in[19];
  const float* cgb1  = (const float*)d_in[20];
  const float* cgg   = (const float*)d_in[21];
  const float* cgbe  = (const float*)d_in[22];
  const float* cgW2  = (const float*)d_in[23];
  const float* cgb2  = (const float*)d_in[24];
  const float* convW = (const float*)d_in[25];
  const float* convB = (const float*)d_in[26];

  float* outp = (float*)d_out;
  __half* reh = (__half*)d_out;        // fp16 [d][l] conv-out lives in d_out rows 1..
  float* wsf  = (float*)d_ws;
  unsigned int* MG = (unsigned int*)wsf;
  __hip_bfloat16* gatedA = (__hip_bfloat16*)wsf;
  char* p = (char*)(wsf + (size_t)NB * NG * NL * ND);
  __hip_bfloat16* Wt2 = (__hip_bfloat16*)p;           p += (size_t)384 * 384 * 3 * 2;
  float* twid = (float*)p;                            p += 2048 * 4;   // 1024 complex
  float* bwp  = (float*)p;                            p += 512 * 4;
  float* dcre = (float*)p;                            p += (size_t)NB * NG * ND * 4;
  __half* W1A = (__half*)p;                           p += (size_t)2 * 36864 * 2;
  __half* W2A = (__half*)p;                           p += (size_t)2 * 36864 * 2;
  __hip_bfloat16* W1G = (__hip_bfloat16*)p;           p += (size_t)147456 * 2;

  k_prep<<<dim3(2932), dim3(256), 0, stream>>>(convW, x, mgW1, phW1, mgW2, phW2, cgW1,
                                               Wt2, twid, W1A, W2A, W1G, outp);
  k_gate2<<<dim3(NB * 64), dim3(256), 0, stream>>>(x, W1G, cgb1, cgg, cgbe, cgW2, cgb2, gatedA);
  k_conv_mfma<<<dim3(NB * NG * 8 * 3), dim3(256), 0, stream>>>(gatedA, Wt2, convB, reh);
  k_fft_fwd<<<dim3(NB * 288), dim3(256), 0, stream>>>(twid, reh, MG, dcre);
  k_bd<<<dim3(NB * NG), dim3(96), 0, stream>>>(dcre, bdW1, bdb1, bdg, bdbe, bdW2, bdb2, bwp);
  k_att7<<<dim3(NB * NG * 32), dim3(256), 0, stream>>>(MG,
      W1A, W2A, mgb1, mgg, mgbe, mgb2, phb1, phg, phbe, phb2, bwp);
  k_fft_inv<<<dim3(NB * 288), dim3(256), 0, stream>>>(twid, MG);
  k_tr<<<dim3(NB * NG * 16 * 6), dim3(256), 0, stream>>>((const __half*)MG, outp);
}